// Round 1
// baseline (3428.012 us; speedup 1.0000x reference)
//
#include <hip/hip_runtime.h>

#define NN 100000
#define NE 1600000
#define DD 128
#define FF 256
static constexpr float EPS_ = 1e-5f;

// ---------------- zero the 6x128 stats accumulators ----------------
__global__ __launch_bounds__(256) void k_zero_stats(float* __restrict__ stats) {
    int t = threadIdx.x;
    for (int i = t; i < 768; i += 256) stats[i] = 0.f;
}

// ---------------- agg = broadcast bias b ----------------
__global__ __launch_bounds__(256) void k_init_agg(const float* __restrict__ b,
                                                  float* __restrict__ agg) {
    int i = blockIdx.x * 256 + threadIdx.x;       // float4 index, NN*DD/4 total
    const float4* b4 = (const float4*)b;
    ((float4*)agg)[i] = b4[i & 31];
}

// ---------------- h = x @ W^T  (W: [D][D] row-major) ----------------
// block 256 threads, 32 rows per block. LDS: xs[32][128] + wT[128][128] (k-major)
__global__ __launch_bounds__(256) void k_gemm1(const float* __restrict__ x,
                                               const float* __restrict__ W,
                                               float* __restrict__ h) {
    __shared__ float xs[32 * 128];     // 16 KB
    __shared__ float wT[128 * 128];    // 64 KB, wT[k*128+o] = W[o*128+k]
    int tid = threadIdx.x;
    int row0 = blockIdx.x * 32;

    {   // stage x tile, coalesced float4
        const float4* xg = (const float4*)(x + (size_t)row0 * DD);
        float4* xl = (float4*)xs;
        for (int i = tid; i < 32 * 32; i += 256) xl[i] = xg[i];
    }
    {   // stage W transposed (global strided reads; LDS writes conflict-free)
        const float4* wg = (const float4*)W;
        for (int i = tid; i < 128 * 32; i += 256) {
            int o  = i & 127;
            int k4 = i >> 7;
            float4 v = wg[o * 32 + k4];
            wT[(4 * k4 + 0) * 128 + o] = v.x;
            wT[(4 * k4 + 1) * 128 + o] = v.y;
            wT[(4 * k4 + 2) * 128 + o] = v.z;
            wT[(4 * k4 + 3) * 128 + o] = v.w;
        }
    }
    __syncthreads();

    int r0 = (tid >> 5) * 4;   // 8 row-groups x 4
    int c4 = tid & 31;         // col-group, cols 4*c4..4*c4+3
    float acc[4][4] = {};
    const float4* wT4 = (const float4*)wT;
    for (int k = 0; k < 128; ++k) {
        float4 wv = wT4[k * 32 + c4];
        float x0 = xs[(r0 + 0) * 128 + k];
        float x1 = xs[(r0 + 1) * 128 + k];
        float x2 = xs[(r0 + 2) * 128 + k];
        float x3 = xs[(r0 + 3) * 128 + k];
        acc[0][0] += x0 * wv.x; acc[0][1] += x0 * wv.y; acc[0][2] += x0 * wv.z; acc[0][3] += x0 * wv.w;
        acc[1][0] += x1 * wv.x; acc[1][1] += x1 * wv.y; acc[1][2] += x1 * wv.z; acc[1][3] += x1 * wv.w;
        acc[2][0] += x2 * wv.x; acc[2][1] += x2 * wv.y; acc[2][2] += x2 * wv.z; acc[2][3] += x2 * wv.w;
        acc[3][0] += x3 * wv.x; acc[3][1] += x3 * wv.y; acc[3][2] += x3 * wv.z; acc[3][3] += x3 * wv.w;
    }
    float4* h4 = (float4*)h;
    for (int i = 0; i < 4; ++i) {
        float4 st = make_float4(acc[i][0], acc[i][1], acc[i][2], acc[i][3]);
        h4[(size_t)(row0 + r0 + i) * 32 + c4] = st;
    }
}

// ---------------- scatter: agg[dst] += relu(h[src] + edge_attr) ----------------
// one thread = one float4 of one edge; wave = 2 edges
__global__ __launch_bounds__(256) void k_scatter(const float* __restrict__ h,
                                                 const float* __restrict__ ea,
                                                 const int* __restrict__ ei,
                                                 float* __restrict__ agg) {
    int gid = blockIdx.x * 256 + threadIdx.x;
    int e = gid >> 5;
    int q = gid & 31;
    if (e >= NE) return;
    int src = ei[e];
    int dst = ei[NE + e];
    float4 hv = ((const float4*)(h + (size_t)src * DD))[q];
    float4 av = ((const float4*)(ea + (size_t)e * DD))[q];
    float4 m;
    m.x = fmaxf(hv.x + av.x, 0.f);
    m.y = fmaxf(hv.y + av.y, 0.f);
    m.z = fmaxf(hv.z + av.z, 0.f);
    m.w = fmaxf(hv.w + av.w, 0.f);
    float* ap = agg + (size_t)dst * DD + q * 4;
    atomicAdd(ap + 0, m.x);
    atomicAdd(ap + 1, m.y);
    atomicAdd(ap + 2, m.z);
    atomicAdd(ap + 3, m.w);
}

// ---------------- per-column sum / sumsq over N rows ----------------
__global__ __launch_bounds__(256) void k_colstats(const float* __restrict__ zin,
                                                  float* __restrict__ sum,
                                                  float* __restrict__ sumsq) {
    __shared__ float ps[256];
    __shared__ float qs[256];
    int tid = threadIdx.x;
    int col = tid & 127;
    int half = tid >> 7;
    int row0 = blockIdx.x * 256;
    int rmax = NN - row0; if (rmax > 256) rmax = 256;
    float a = 0.f, b = 0.f;
    for (int r = half; r < rmax; r += 2) {
        float v = zin[(size_t)(row0 + r) * DD + col];
        a += v;
        b += v * v;
    }
    ps[tid] = a; qs[tid] = b;
    __syncthreads();
    if (tid < 128) {
        atomicAdd(&sum[col],   ps[tid] + ps[tid + 128]);
        atomicAdd(&sumsq[col], qs[tid] + qs[tid + 128]);
    }
}

// ---------------- y1 = x + relu(bn1(agg)) ----------------
__global__ __launch_bounds__(256) void k_y1(const float* __restrict__ x,
                                            const float* __restrict__ agg,
                                            const float* __restrict__ stats,   // [0:128]=sum, [128:256]=sumsq
                                            const float* __restrict__ g,
                                            const float* __restrict__ bb,
                                            float* __restrict__ y1) {
    int tid = threadIdx.x;
    int c0 = (tid & 31) * 4;
    float A[4], C[4];
    for (int j = 0; j < 4; ++j) {
        int c = c0 + j;
        float m = stats[c] * (1.f / NN);
        float v = stats[128 + c] * (1.f / NN) - m * m;
        float inv = rsqrtf(v + EPS_);
        A[j] = inv * g[c];
        C[j] = bb[c] - m * inv * g[c];
    }
    const float4* x4 = (const float4*)x;
    const float4* a4 = (const float4*)agg;
    float4* y4 = (float4*)y1;
    int step = gridDim.x * 256;
    for (int i = blockIdx.x * 256 + tid; i < NN * 32; i += step) {
        float4 av = a4[i];
        float4 xv = x4[i];
        float4 r;
        r.x = xv.x + fmaxf(av.x * A[0] + C[0], 0.f);
        r.y = xv.y + fmaxf(av.y * A[1] + C[1], 0.f);
        r.z = xv.z + fmaxf(av.z * A[2] + C[2], 0.f);
        r.w = xv.w + fmaxf(av.w * A[3] + C[3], 0.f);
        y4[i] = r;
    }
}

// ---------------- fused FFN: z = y2 + (relu(y2@W1^T+b1))@W2^T + b2,  y2 = bnl(y1) ----------------
// block 256 threads, 32 rows. LDS: ys 16KB + wbuf 32KB (shared W1/W2 chunks) + hs 32KB = 80KB
__global__ __launch_bounds__(256) void k_ffn(const float* __restrict__ y1,
                                             const float* __restrict__ stats2,
                                             const float* __restrict__ g2,
                                             const float* __restrict__ bl2,
                                             const float* __restrict__ W1,
                                             const float* __restrict__ b1,
                                             const float* __restrict__ W2,
                                             const float* __restrict__ b2f,
                                             float* __restrict__ z) {
    __shared__ float ys[32 * 128];    // normalized y2 tile
    __shared__ float wbuf[8192];      // W1 chunk [128k][64f] or W2 chunk [256f][32o]
    __shared__ float hs[32 * 256];    // hidden tile
    int tid = threadIdx.x;
    int row0 = blockIdx.x * 32;

    {   // phase A: load + bnl-normalize
        int col = tid & 127;
        float m = stats2[col] * (1.f / NN);
        float v = stats2[128 + col] * (1.f / NN) - m * m;
        float inv = rsqrtf(v + EPS_);
        float Aa = inv * g2[col];
        float Cc = bl2[col] - m * inv * g2[col];
        for (int i = tid; i < 32 * 128; i += 256) {
            int r = i >> 7;
            ys[i] = y1[(size_t)(row0 + r) * DD + col] * Aa + Cc;
        }
    }
    __syncthreads();

    int r0 = (tid >> 4) * 2;   // 16 row-groups x 2
    int cg = tid & 15;

    // phase B: hidden = relu(y2 @ W1^T + b1), 4 chunks of 64 hidden cols
    for (int hc = 0; hc < 4; ++hc) {
        for (int i = tid; i < 2048; i += 256) {
            int f  = i & 63;
            int k4 = i >> 6;
            float4 v = ((const float4*)W1)[(hc * 64 + f) * 32 + k4];
            wbuf[(4 * k4 + 0) * 64 + f] = v.x;
            wbuf[(4 * k4 + 1) * 64 + f] = v.y;
            wbuf[(4 * k4 + 2) * 64 + f] = v.z;
            wbuf[(4 * k4 + 3) * 64 + f] = v.w;
        }
        __syncthreads();
        float acc[2][4] = {};
        const float4* w4 = (const float4*)wbuf;
        for (int k = 0; k < 128; ++k) {
            float4 wv = w4[k * 16 + cg];
            float ya = ys[(r0 + 0) * 128 + k];
            float yb = ys[(r0 + 1) * 128 + k];
            acc[0][0] += ya * wv.x; acc[0][1] += ya * wv.y; acc[0][2] += ya * wv.z; acc[0][3] += ya * wv.w;
            acc[1][0] += yb * wv.x; acc[1][1] += yb * wv.y; acc[1][2] += yb * wv.z; acc[1][3] += yb * wv.w;
        }
        int fbase = hc * 64 + cg * 4;
        for (int i2 = 0; i2 < 2; ++i2) {
            float4 hv;
            hv.x = fmaxf(acc[i2][0] + b1[fbase + 0], 0.f);
            hv.y = fmaxf(acc[i2][1] + b1[fbase + 1], 0.f);
            hv.z = fmaxf(acc[i2][2] + b1[fbase + 2], 0.f);
            hv.w = fmaxf(acc[i2][3] + b1[fbase + 3], 0.f);
            ((float4*)hs)[(r0 + i2) * 64 + hc * 16 + cg] = hv;
        }
        __syncthreads();
    }

    // phase C: out = hidden @ W2^T + b2; z = y2 + out.  4 chunks of 32 out cols
    for (int oc = 0; oc < 4; ++oc) {
        for (int i = tid; i < 2048; i += 256) {
            int o  = i & 31;
            int f4 = i >> 5;
            float4 v = ((const float4*)W2)[(oc * 32 + o) * 64 + f4];
            wbuf[(4 * f4 + 0) * 32 + o] = v.x;
            wbuf[(4 * f4 + 1) * 32 + o] = v.y;
            wbuf[(4 * f4 + 2) * 32 + o] = v.z;
            wbuf[(4 * f4 + 3) * 32 + o] = v.w;
        }
        __syncthreads();
        float acc[2][2] = {};
        const float2* w2p = (const float2*)wbuf;
        for (int f = 0; f < 256; ++f) {
            float2 wv = w2p[f * 16 + cg];
            float ha = hs[(r0 + 0) * 256 + f];
            float hb = hs[(r0 + 1) * 256 + f];
            acc[0][0] += ha * wv.x; acc[0][1] += ha * wv.y;
            acc[1][0] += hb * wv.x; acc[1][1] += hb * wv.y;
        }
        int obase = oc * 32 + cg * 2;
        for (int i2 = 0; i2 < 2; ++i2) {
            int rr = row0 + r0 + i2;
            float z0 = ys[(r0 + i2) * 128 + obase + 0] + acc[i2][0] + b2f[obase + 0];
            float z1 = ys[(r0 + i2) * 128 + obase + 1] + acc[i2][1] + b2f[obase + 1];
            ((float2*)z)[(size_t)rr * 64 + (obase >> 1)] = make_float2(z0, z1);
        }
        __syncthreads();
    }
}

// ---------------- out = bn2(z) ----------------
__global__ __launch_bounds__(256) void k_out(const float* __restrict__ zin,
                                             const float* __restrict__ stats,
                                             const float* __restrict__ g,
                                             const float* __restrict__ bb,
                                             float* __restrict__ outp) {
    int tid = threadIdx.x;
    int c0 = (tid & 31) * 4;
    float A[4], C[4];
    for (int j = 0; j < 4; ++j) {
        int c = c0 + j;
        float m = stats[c] * (1.f / NN);
        float v = stats[128 + c] * (1.f / NN) - m * m;
        float inv = rsqrtf(v + EPS_);
        A[j] = inv * g[c];
        C[j] = bb[c] - m * inv * g[c];
    }
    const float4* z4 = (const float4*)zin;
    float4* o4 = (float4*)outp;
    int step = gridDim.x * 256;
    for (int i = blockIdx.x * 256 + tid; i < NN * 32; i += step) {
        float4 zv = z4[i];
        float4 r;
        r.x = zv.x * A[0] + C[0];
        r.y = zv.y * A[1] + C[1];
        r.z = zv.z * A[2] + C[2];
        r.w = zv.w * A[3] + C[3];
        o4[i] = r;
    }
}

extern "C" void kernel_launch(void* const* d_in, const int* in_sizes, int n_in,
                              void* d_out, int out_size, void* d_ws, size_t ws_size,
                              hipStream_t stream) {
    const float* x     = (const float*)d_in[0];
    const float* ea    = (const float*)d_in[1];
    const float* W     = (const float*)d_in[2];
    const float* b     = (const float*)d_in[3];
    const float* bn_g  = (const float*)d_in[4];
    const float* bn_b  = (const float*)d_in[5];
    const float* bnl_g = (const float*)d_in[6];
    const float* bnl_b = (const float*)d_in[7];
    const float* bn2_g = (const float*)d_in[8];
    const float* bn2_b = (const float*)d_in[9];
    const float* W1    = (const float*)d_in[10];
    const float* b1    = (const float*)d_in[11];
    const float* W2    = (const float*)d_in[12];
    const float* b2    = (const float*)d_in[13];
    const int*   ei    = (const int*)d_in[14];
    float* out = (float*)d_out;

    float* bufA  = (float*)d_ws;                      // h, later z
    float* bufB  = bufA + (size_t)NN * DD;            // agg
    float* stats = bufB + (size_t)NN * DD;            // 6 x 128 floats
    float* s1 = stats;
    float* s2 = stats + 256;
    float* s3 = stats + 512;

    hipLaunchKernelGGL(k_zero_stats, dim3(1),      dim3(256), 0, stream, stats);
    hipLaunchKernelGGL(k_init_agg,   dim3(12500),  dim3(256), 0, stream, b, bufB);
    hipLaunchKernelGGL(k_gemm1,      dim3(3125),   dim3(256), 0, stream, x, W, bufA);
    hipLaunchKernelGGL(k_scatter,    dim3(200000), dim3(256), 0, stream, bufA, ea, ei, bufB);
    hipLaunchKernelGGL(k_colstats,   dim3(391),    dim3(256), 0, stream, bufB, s1, s1 + 128);
    hipLaunchKernelGGL(k_y1,         dim3(2048),   dim3(256), 0, stream, x, bufB, s1, bn_g, bn_b, out);
    hipLaunchKernelGGL(k_colstats,   dim3(391),    dim3(256), 0, stream, out, s2, s2 + 128);
    hipLaunchKernelGGL(k_ffn,        dim3(3125),   dim3(256), 0, stream, out, s2, bnl_g, bnl_b,
                       W1, b1, W2, b2, bufA);
    hipLaunchKernelGGL(k_colstats,   dim3(391),    dim3(256), 0, stream, bufA, s3, s3 + 128);
    hipLaunchKernelGGL(k_out,        dim3(2048),   dim3(256), 0, stream, bufA, s3, bn2_g, bn2_b, out);
}

// Round 2
// 1426.204 us; speedup vs baseline: 2.4036x; 2.4036x over previous
//
#include <hip/hip_runtime.h>
#include <hip/hip_bf16.h>

#define NN 100000
#define NE 1600000
#define DD 128
#define FF 256
static constexpr float EPS_ = 1e-5f;

__device__ inline unsigned short f2bf(float f) {
    __hip_bfloat16 h = __float2bfloat16(f);
    return *reinterpret_cast<unsigned short*>(&h);
}
__device__ inline float bflo(unsigned int u) { return __uint_as_float(u << 16); }
__device__ inline float bfhi(unsigned int u) { return __uint_as_float(u & 0xFFFF0000u); }

// ---------------- zero the 6x128 stats accumulators ----------------
__global__ __launch_bounds__(256) void k_zero_stats(float* __restrict__ stats) {
    int t = threadIdx.x;
    for (int i = t; i < 768; i += 256) stats[i] = 0.f;
}

// ---------------- zero deg[N] ----------------
__global__ __launch_bounds__(256) void k_zero_int(int* __restrict__ p) {
    int i = blockIdx.x * 256 + threadIdx.x;
    if (i < NN) p[i] = 0;
}

// ---------------- h = x @ W^T -> bf16  (W: [D][D] row-major) ----------------
__global__ __launch_bounds__(256) void k_gemm1(const float* __restrict__ x,
                                               const float* __restrict__ W,
                                               unsigned short* __restrict__ h2) {
    __shared__ float xs[32 * 128];     // 16 KB
    __shared__ float wT[128 * 128];    // 64 KB, wT[k*128+o] = W[o*128+k]
    int tid = threadIdx.x;
    int row0 = blockIdx.x * 32;

    {   // stage x tile, coalesced float4
        const float4* xg = (const float4*)(x + (size_t)row0 * DD);
        float4* xl = (float4*)xs;
        for (int i = tid; i < 32 * 32; i += 256) xl[i] = xg[i];
    }
    {   // stage W transposed
        const float4* wg = (const float4*)W;
        for (int i = tid; i < 128 * 32; i += 256) {
            int o  = i & 127;
            int k4 = i >> 7;
            float4 v = wg[o * 32 + k4];
            wT[(4 * k4 + 0) * 128 + o] = v.x;
            wT[(4 * k4 + 1) * 128 + o] = v.y;
            wT[(4 * k4 + 2) * 128 + o] = v.z;
            wT[(4 * k4 + 3) * 128 + o] = v.w;
        }
    }
    __syncthreads();

    int r0 = (tid >> 5) * 4;   // 8 row-groups x 4
    int c4 = tid & 31;         // cols 4*c4..4*c4+3
    float acc[4][4] = {};
    const float4* wT4 = (const float4*)wT;
    for (int k = 0; k < 128; ++k) {
        float4 wv = wT4[k * 32 + c4];
        float x0 = xs[(r0 + 0) * 128 + k];
        float x1 = xs[(r0 + 1) * 128 + k];
        float x2 = xs[(r0 + 2) * 128 + k];
        float x3 = xs[(r0 + 3) * 128 + k];
        acc[0][0] += x0 * wv.x; acc[0][1] += x0 * wv.y; acc[0][2] += x0 * wv.z; acc[0][3] += x0 * wv.w;
        acc[1][0] += x1 * wv.x; acc[1][1] += x1 * wv.y; acc[1][2] += x1 * wv.z; acc[1][3] += x1 * wv.w;
        acc[2][0] += x2 * wv.x; acc[2][1] += x2 * wv.y; acc[2][2] += x2 * wv.z; acc[2][3] += x2 * wv.w;
        acc[3][0] += x3 * wv.x; acc[3][1] += x3 * wv.y; acc[3][2] += x3 * wv.z; acc[3][3] += x3 * wv.w;
    }
    for (int i = 0; i < 4; ++i) {
        ushort4 st = make_ushort4(f2bf(acc[i][0]), f2bf(acc[i][1]), f2bf(acc[i][2]), f2bf(acc[i][3]));
        ((ushort4*)h2)[(size_t)(row0 + r0 + i) * 32 + c4] = st;
    }
}

// ---------------- deg histogram over dst ----------------
__global__ __launch_bounds__(256) void k_hist(const int* __restrict__ ei,
                                              int* __restrict__ deg) {
    int e = blockIdx.x * 256 + threadIdx.x;
    if (e < NE) atomicAdd(&deg[ei[NE + e]], 1);
}

// ---------------- in-place exclusive scan of deg[N] (single block) ----------------
__global__ __launch_bounds__(1024) void k_scan(int* __restrict__ p) {
    __shared__ int part[1024];
    int t = threadIdx.x;
    const int CH = (NN + 1023) / 1024;   // 98
    int i0 = t * CH;
    int iend = i0 + CH; if (iend > NN) iend = NN; if (i0 > NN) i0 = NN;
    int s = 0;
    for (int i = i0; i < iend; ++i) s += p[i];
    part[t] = s;
    __syncthreads();
    for (int d = 1; d < 1024; d <<= 1) {
        int add = (t >= d) ? part[t - d] : 0;
        __syncthreads();
        part[t] += add;
        __syncthreads();
    }
    int off = (t == 0) ? 0 : part[t - 1];
    for (int i = i0; i < iend; ++i) {
        int v = p[i];
        p[i] = off;
        off += v;
    }
}

// ---------------- fill eidx sorted by dst; ptr[i] becomes END offset of node i ----------------
__global__ __launch_bounds__(256) void k_fill(const int* __restrict__ ei,
                                              int* __restrict__ ptr,
                                              int* __restrict__ eidx) {
    int e = blockIdx.x * 256 + threadIdx.x;
    if (e >= NE) return;
    int d = ei[NE + e];
    int pos = atomicAdd(&ptr[d], 1);
    eidx[pos] = e;
}

// ---------------- gather-side aggregation: agg[i] = b + sum relu(h[src]+ea[e]) ----------------
// one wave (64 lanes) per node, 2 cols per lane
__global__ __launch_bounds__(256) void k_gather(const unsigned short* __restrict__ h2,
                                                const float* __restrict__ ea,
                                                const int* __restrict__ ei,
                                                const int* __restrict__ ptr,
                                                const int* __restrict__ eidx,
                                                const float* __restrict__ bias,
                                                float* __restrict__ agg) {
    int w = (blockIdx.x * 256 + threadIdx.x) >> 6;   // node
    int lane = threadIdx.x & 63;
    if (w >= NN) return;
    int beg = (w == 0) ? 0 : ptr[w - 1];
    int end = ptr[w];
    float ax = 0.f, ay = 0.f;
    const unsigned int* h2u = (const unsigned int*)h2;
    for (int j = beg; j < end; ++j) {
        int e = eidx[j];
        int src = ei[e];
        unsigned int hh = h2u[(size_t)src * 64 + lane];
        float2 av = ((const float2*)(ea + (size_t)e * DD))[lane];
        ax += fmaxf(bflo(hh) + av.x, 0.f);
        ay += fmaxf(bfhi(hh) + av.y, 0.f);
    }
    float2 bv = ((const float2*)bias)[lane];
    ((float2*)(agg + (size_t)w * DD))[lane] = make_float2(ax + bv.x, ay + bv.y);
}

// ---------------- per-column sum / sumsq over N rows ----------------
__global__ __launch_bounds__(256) void k_colstats(const float* __restrict__ zin,
                                                  float* __restrict__ sum,
                                                  float* __restrict__ sumsq) {
    __shared__ float ps[256];
    __shared__ float qs[256];
    int tid = threadIdx.x;
    int col = tid & 127;
    int half = tid >> 7;
    int row0 = blockIdx.x * 256;
    int rmax = NN - row0; if (rmax > 256) rmax = 256;
    float a = 0.f, b = 0.f;
    for (int r = half; r < rmax; r += 2) {
        float v = zin[(size_t)(row0 + r) * DD + col];
        a += v;
        b += v * v;
    }
    ps[tid] = a; qs[tid] = b;
    __syncthreads();
    if (tid < 128) {
        atomicAdd(&sum[col],   ps[tid] + ps[tid + 128]);
        atomicAdd(&sumsq[col], qs[tid] + qs[tid + 128]);
    }
}

// ---------------- y1 = x + relu(bn1(agg)) ----------------
__global__ __launch_bounds__(256) void k_y1(const float* __restrict__ x,
                                            const float* __restrict__ agg,
                                            const float* __restrict__ stats,
                                            const float* __restrict__ g,
                                            const float* __restrict__ bb,
                                            float* __restrict__ y1) {
    int tid = threadIdx.x;
    int c0 = (tid & 31) * 4;
    float A[4], C[4];
    for (int j = 0; j < 4; ++j) {
        int c = c0 + j;
        float m = stats[c] * (1.f / NN);
        float v = stats[128 + c] * (1.f / NN) - m * m;
        float inv = rsqrtf(v + EPS_);
        A[j] = inv * g[c];
        C[j] = bb[c] - m * inv * g[c];
    }
    const float4* x4 = (const float4*)x;
    const float4* a4 = (const float4*)agg;
    float4* y4 = (float4*)y1;
    int step = gridDim.x * 256;
    for (int i = blockIdx.x * 256 + tid; i < NN * 32; i += step) {
        float4 av = a4[i];
        float4 xv = x4[i];
        float4 r;
        r.x = xv.x + fmaxf(av.x * A[0] + C[0], 0.f);
        r.y = xv.y + fmaxf(av.y * A[1] + C[1], 0.f);
        r.z = xv.z + fmaxf(av.z * A[2] + C[2], 0.f);
        r.w = xv.w + fmaxf(av.w * A[3] + C[3], 0.f);
        y4[i] = r;
    }
}

// ---------------- fused FFN: z = y2 + (relu(y2@W1^T+b1))@W2^T + b2,  y2 = bnl(y1) ----------------
__global__ __launch_bounds__(256) void k_ffn(const float* __restrict__ y1,
                                             const float* __restrict__ stats2,
                                             const float* __restrict__ g2,
                                             const float* __restrict__ bl2,
                                             const float* __restrict__ W1,
                                             const float* __restrict__ b1,
                                             const float* __restrict__ W2,
                                             const float* __restrict__ b2f,
                                             float* __restrict__ z) {
    __shared__ float ys[32 * 128];    // normalized y2 tile
    __shared__ float wbuf[8192];      // W1 chunk [128k][64f] or W2 chunk [256f][32o]
    __shared__ float hs[32 * 256];    // hidden tile
    int tid = threadIdx.x;
    int row0 = blockIdx.x * 32;

    {   // phase A: load + bnl-normalize
        int col = tid & 127;
        float m = stats2[col] * (1.f / NN);
        float v = stats2[128 + col] * (1.f / NN) - m * m;
        float inv = rsqrtf(v + EPS_);
        float Aa = inv * g2[col];
        float Cc = bl2[col] - m * inv * g2[col];
        for (int i = tid; i < 32 * 128; i += 256) {
            int r = i >> 7;
            ys[i] = y1[(size_t)(row0 + r) * DD + col] * Aa + Cc;
        }
    }
    __syncthreads();

    int r0 = (tid >> 4) * 2;   // 16 row-groups x 2
    int cg = tid & 15;

    // phase B: hidden = relu(y2 @ W1^T + b1), 4 chunks of 64 hidden cols
    for (int hc = 0; hc < 4; ++hc) {
        for (int i = tid; i < 2048; i += 256) {
            int f  = i & 63;
            int k4 = i >> 6;
            float4 v = ((const float4*)W1)[(hc * 64 + f) * 32 + k4];
            wbuf[(4 * k4 + 0) * 64 + f] = v.x;
            wbuf[(4 * k4 + 1) * 64 + f] = v.y;
            wbuf[(4 * k4 + 2) * 64 + f] = v.z;
            wbuf[(4 * k4 + 3) * 64 + f] = v.w;
        }
        __syncthreads();
        float acc[2][4] = {};
        const float4* w4 = (const float4*)wbuf;
        for (int k = 0; k < 128; ++k) {
            float4 wv = w4[k * 16 + cg];
            float ya = ys[(r0 + 0) * 128 + k];
            float yb = ys[(r0 + 1) * 128 + k];
            acc[0][0] += ya * wv.x; acc[0][1] += ya * wv.y; acc[0][2] += ya * wv.z; acc[0][3] += ya * wv.w;
            acc[1][0] += yb * wv.x; acc[1][1] += yb * wv.y; acc[1][2] += yb * wv.z; acc[1][3] += yb * wv.w;
        }
        int fbase = hc * 64 + cg * 4;
        for (int i2 = 0; i2 < 2; ++i2) {
            float4 hv;
            hv.x = fmaxf(acc[i2][0] + b1[fbase + 0], 0.f);
            hv.y = fmaxf(acc[i2][1] + b1[fbase + 1], 0.f);
            hv.z = fmaxf(acc[i2][2] + b1[fbase + 2], 0.f);
            hv.w = fmaxf(acc[i2][3] + b1[fbase + 3], 0.f);
            ((float4*)hs)[(r0 + i2) * 64 + hc * 16 + cg] = hv;
        }
        __syncthreads();
    }

    // phase C: out = hidden @ W2^T + b2; z = y2 + out
    for (int oc = 0; oc < 4; ++oc) {
        for (int i = tid; i < 2048; i += 256) {
            int o  = i & 31;
            int f4 = i >> 5;
            float4 v = ((const float4*)W2)[(oc * 32 + o) * 64 + f4];
            wbuf[(4 * f4 + 0) * 32 + o] = v.x;
            wbuf[(4 * f4 + 1) * 32 + o] = v.y;
            wbuf[(4 * f4 + 2) * 32 + o] = v.z;
            wbuf[(4 * f4 + 3) * 32 + o] = v.w;
        }
        __syncthreads();
        float acc[2][2] = {};
        const float2* w2p = (const float2*)wbuf;
        for (int f = 0; f < 256; ++f) {
            float2 wv = w2p[f * 16 + cg];
            float ha = hs[(r0 + 0) * 256 + f];
            float hb = hs[(r0 + 1) * 256 + f];
            acc[0][0] += ha * wv.x; acc[0][1] += ha * wv.y;
            acc[1][0] += hb * wv.x; acc[1][1] += hb * wv.y;
        }
        int obase = oc * 32 + cg * 2;
        for (int i2 = 0; i2 < 2; ++i2) {
            int rr = row0 + r0 + i2;
            float z0 = ys[(r0 + i2) * 128 + obase + 0] + acc[i2][0] + b2f[obase + 0];
            float z1 = ys[(r0 + i2) * 128 + obase + 1] + acc[i2][1] + b2f[obase + 1];
            ((float2*)z)[(size_t)rr * 64 + (obase >> 1)] = make_float2(z0, z1);
        }
        __syncthreads();
    }
}

// ---------------- out = bn2(z) ----------------
__global__ __launch_bounds__(256) void k_out(const float* __restrict__ zin,
                                             const float* __restrict__ stats,
                                             const float* __restrict__ g,
                                             const float* __restrict__ bb,
                                             float* __restrict__ outp) {
    int tid = threadIdx.x;
    int c0 = (tid & 31) * 4;
    float A[4], C[4];
    for (int j = 0; j < 4; ++j) {
        int c = c0 + j;
        float m = stats[c] * (1.f / NN);
        float v = stats[128 + c] * (1.f / NN) - m * m;
        float inv = rsqrtf(v + EPS_);
        A[j] = inv * g[c];
        C[j] = bb[c] - m * inv * g[c];
    }
    const float4* z4 = (const float4*)zin;
    float4* o4 = (float4*)outp;
    int step = gridDim.x * 256;
    for (int i = blockIdx.x * 256 + tid; i < NN * 32; i += step) {
        float4 zv = z4[i];
        float4 r;
        r.x = zv.x * A[0] + C[0];
        r.y = zv.y * A[1] + C[1];
        r.z = zv.z * A[2] + C[2];
        r.w = zv.w * A[3] + C[3];
        o4[i] = r;
    }
}

extern "C" void kernel_launch(void* const* d_in, const int* in_sizes, int n_in,
                              void* d_out, int out_size, void* d_ws, size_t ws_size,
                              hipStream_t stream) {
    const float* x     = (const float*)d_in[0];
    const float* ea    = (const float*)d_in[1];
    const float* W     = (const float*)d_in[2];
    const float* b     = (const float*)d_in[3];
    const float* bn_g  = (const float*)d_in[4];
    const float* bn_b  = (const float*)d_in[5];
    const float* bnl_g = (const float*)d_in[6];
    const float* bnl_b = (const float*)d_in[7];
    const float* bn2_g = (const float*)d_in[8];
    const float* bn2_b = (const float*)d_in[9];
    const float* W1    = (const float*)d_in[10];
    const float* b1    = (const float*)d_in[11];
    const float* W2    = (const float*)d_in[12];
    const float* b2    = (const float*)d_in[13];
    const int*   ei    = (const int*)d_in[14];
    float* out = (float*)d_out;

    char* base = (char*)d_ws;
    // region A [0, 51.2MB): h_bf16 (25.6MB) + deg (400KB) + eidx (6.4MB); later z f32 (full)
    unsigned short* h2  = (unsigned short*)base;
    int*   deg  = (int*)(base + 25600000);
    int*   eidx = (int*)(base + 26000000);
    float* z    = (float*)base;
    // region B [51.2MB, 102.4MB): agg f32
    float* agg  = (float*)(base + (size_t)NN * DD * 4);
    // stats [102.4MB, +3KB)
    float* stats = (float*)(base + (size_t)2 * NN * DD * 4);
    float* s1 = stats;
    float* s2 = stats + 256;
    float* s3 = stats + 512;

    hipLaunchKernelGGL(k_zero_stats, dim3(1),     dim3(256),  0, stream, stats);
    hipLaunchKernelGGL(k_zero_int,   dim3(391),   dim3(256),  0, stream, deg);
    hipLaunchKernelGGL(k_gemm1,      dim3(3125),  dim3(256),  0, stream, x, W, h2);
    hipLaunchKernelGGL(k_hist,       dim3(6250),  dim3(256),  0, stream, ei, deg);
    hipLaunchKernelGGL(k_scan,       dim3(1),     dim3(1024), 0, stream, deg);
    hipLaunchKernelGGL(k_fill,       dim3(6250),  dim3(256),  0, stream, ei, deg, eidx);
    hipLaunchKernelGGL(k_gather,     dim3(25000), dim3(256),  0, stream, h2, ea, ei, deg, eidx, b, agg);
    hipLaunchKernelGGL(k_colstats,   dim3(391),   dim3(256),  0, stream, agg, s1, s1 + 128);
    hipLaunchKernelGGL(k_y1,         dim3(2048),  dim3(256),  0, stream, x, agg, s1, bn_g, bn_b, out);
    hipLaunchKernelGGL(k_colstats,   dim3(391),   dim3(256),  0, stream, out, s2, s2 + 128);
    hipLaunchKernelGGL(k_ffn,        dim3(3125),  dim3(256),  0, stream, out, s2, bnl_g, bnl_b,
                       W1, b1, W2, b2, z);
    hipLaunchKernelGGL(k_colstats,   dim3(391),   dim3(256),  0, stream, z, s3, s3 + 128);
    hipLaunchKernelGGL(k_out,        dim3(2048),  dim3(256),  0, stream, z, s3, bn2_g, bn2_b, out);
}

// Round 3
// 991.933 us; speedup vs baseline: 3.4559x; 1.4378x over previous
//
#include <hip/hip_runtime.h>
#include <hip/hip_bf16.h>

#define NN 100000
#define NE 1600000
#define DD 128
#define FF 256
static constexpr float EPS_ = 1e-5f;

typedef __bf16 bf16x4 __attribute__((ext_vector_type(4)));
typedef __bf16 bf16x8 __attribute__((ext_vector_type(8)));
typedef float  f32x4  __attribute__((ext_vector_type(4)));

__device__ inline float bflo(unsigned int u) { return __uint_as_float(u << 16); }
__device__ inline float bfhi(unsigned int u) { return __uint_as_float(u & 0xFFFF0000u); }

// ---------------- zero the 6x128 stats accumulators ----------------
__global__ __launch_bounds__(256) void k_zero_stats(float* __restrict__ stats) {
    int t = threadIdx.x;
    for (int i = t; i < 768; i += 256) stats[i] = 0.f;
}

// ---------------- zero deg[N] ----------------
__global__ __launch_bounds__(256) void k_zero_int(int* __restrict__ p) {
    int i = blockIdx.x * 256 + threadIdx.x;
    if (i < NN) p[i] = 0;
}

// ---------------- fp32 -> bf16 weight copies ----------------
__global__ __launch_bounds__(256) void k_prepw(const float* __restrict__ W,
                                               const float* __restrict__ W1,
                                               const float* __restrict__ W2,
                                               __bf16* __restrict__ Wb,
                                               __bf16* __restrict__ W1b,
                                               __bf16* __restrict__ W2b) {
    int i = blockIdx.x * 256 + threadIdx.x;
    if (i < 16384) Wb[i] = (__bf16)W[i];
    if (i >= 16384 && i < 49152) W1b[i - 16384] = (__bf16)W1[i - 16384];
    if (i >= 49152 && i < 81920) W2b[i - 49152] = (__bf16)W2[i - 49152];
}

// ---------------- h = x @ W^T -> bf16, via MFMA ----------------
// block = 256 thr (4 waves), 64 rows; wave w owns rows m0=w*16 .. m0+15
__global__ __launch_bounds__(256) void k_gemmx(const float* __restrict__ x,
                                               const __bf16* __restrict__ Wb,
                                               __bf16* __restrict__ h2) {
    __shared__ __bf16 xs[64 * 128];   // swizzled bf16 x tile; later reused as output staging
    int tid = threadIdx.x;
    int row0 = blockIdx.x * 64;
    int V = NN - row0; if (V > 64) V = 64;

    {   // fill xs (coalesced float4 reads, swizzled bf16 stores)
        int c0 = (tid & 31) * 4;
        for (int j = 0; j < 8; ++j) {
            int idx = j * 256 + tid;
            int r = idx >> 5;
            float4 v = make_float4(0.f, 0.f, 0.f, 0.f);
            if (r < V) v = ((const float4*)(x + (size_t)row0 * DD))[idx];
            bf16x4 bv; bv[0] = (__bf16)v.x; bv[1] = (__bf16)v.y; bv[2] = (__bf16)v.z; bv[3] = (__bf16)v.w;
            int sw = (((c0 >> 3) ^ (r & 7)) << 3) + (c0 & 7);
            *reinterpret_cast<bf16x4*>(&xs[r * 128 + sw]) = bv;
        }
    }
    __syncthreads();

    int l = tid & 63, w = tid >> 6;
    int m0 = w * 16, lr = l & 15, lk = (l >> 4) * 8;
    int mrow = m0 + lr;

    bf16x8 a[4];
    for (int kk = 0; kk < 4; ++kk) {
        int k = kk * 32 + lk;
        int sw = ((k >> 3) ^ (mrow & 7)) << 3;
        a[kk] = *reinterpret_cast<const bf16x8*>(&xs[mrow * 128 + sw]);
    }
    for (int nt = 0; nt < 8; ++nt) {
        int n0 = nt * 16;
        f32x4 acc = {0.f, 0.f, 0.f, 0.f};
        for (int kk = 0; kk < 4; ++kk) {
            bf16x8 b = *reinterpret_cast<const bf16x8*>(&Wb[(n0 + lr) * 128 + kk * 32 + lk]);
            acc = __builtin_amdgcn_mfma_f32_16x16x32_bf16(a[kk], b, acc, 0, 0, 0);
        }
        int n = n0 + lr;
#pragma unroll
        for (int r = 0; r < 4; ++r) {
            int m = m0 + (l >> 4) * 4 + r;
            xs[m * 128 + n] = (__bf16)acc[r];   // unswizzled, own rows only
        }
    }
    // coalesced copy of own 16 rows to global
    for (int i = 0; i < 8; ++i) {
        int j = i * 64 + l;          // 0..511 over 16 rows x 32 bf16x4
        int rl = j >> 5;
        int c4 = j & 31;
        int m = m0 + rl;
        if (row0 + m < NN) {
            bf16x4 v = *reinterpret_cast<const bf16x4*>(&xs[m * 128 + c4 * 4]);
            *reinterpret_cast<bf16x4*>(&h2[(size_t)(row0 + m) * 128 + c4 * 4]) = v;
        }
    }
}

// ---------------- deg histogram over dst ----------------
__global__ __launch_bounds__(256) void k_hist(const int* __restrict__ ei,
                                              int* __restrict__ deg) {
    int e = blockIdx.x * 256 + threadIdx.x;
    if (e < NE) atomicAdd(&deg[ei[NE + e]], 1);
}

// ---------------- in-place exclusive scan of deg[N] (single block) ----------------
__global__ __launch_bounds__(1024) void k_scan(int* __restrict__ p) {
    __shared__ int part[1024];
    int t = threadIdx.x;
    const int CH = (NN + 1023) / 1024;   // 98
    int i0 = t * CH;
    int iend = i0 + CH; if (iend > NN) iend = NN; if (i0 > NN) i0 = NN;
    int s = 0;
    for (int i = i0; i < iend; ++i) s += p[i];
    part[t] = s;
    __syncthreads();
    for (int d = 1; d < 1024; d <<= 1) {
        int add = (t >= d) ? part[t - d] : 0;
        __syncthreads();
        part[t] += add;
        __syncthreads();
    }
    int off = (t == 0) ? 0 : part[t - 1];
    for (int i = i0; i < iend; ++i) {
        int v = p[i];
        p[i] = off;
        off += v;
    }
}

// ---------------- fill eidx sorted by dst; ptr[i] becomes END offset ----------------
__global__ __launch_bounds__(256) void k_fill(const int* __restrict__ ei,
                                              int* __restrict__ ptr,
                                              int* __restrict__ eidx) {
    int e = blockIdx.x * 256 + threadIdx.x;
    if (e >= NE) return;
    int d = ei[NE + e];
    int pos = atomicAdd(&ptr[d], 1);
    eidx[pos] = e;
}

// ---------------- gather: agg[i] = b + sum relu(h[src]+ea[e]); fused s1 stats ----------------
__global__ __launch_bounds__(256) void k_gather(const unsigned int* __restrict__ h2u,
                                                const float* __restrict__ ea,
                                                const int* __restrict__ ei,
                                                const int* __restrict__ ptr,
                                                const int* __restrict__ eidx,
                                                const float* __restrict__ bias,
                                                float* __restrict__ agg,
                                                float* __restrict__ s1) {
    __shared__ float zs[128], zq[128];
    int tid = threadIdx.x;
    if (tid < 128) { zs[tid] = 0.f; zq[tid] = 0.f; }
    __syncthreads();
    int lane = tid & 63;
    int wglob = blockIdx.x * 4 + (tid >> 6);
    int nwaves = gridDim.x * 4;
    float2 bv = ((const float2*)bias)[lane];
    float sx = 0.f, qx = 0.f, sy = 0.f, qy = 0.f;
    for (int w = wglob; w < NN; w += nwaves) {
        int beg = (w == 0) ? 0 : ptr[w - 1];
        int end = ptr[w];
        float ax = 0.f, ay = 0.f;
        int e = 0, src = 0;
        if (beg < end) { e = eidx[beg]; src = ei[e]; }
        for (int j = beg; j < end; ++j) {
            int en = 0, sn = 0;
            if (j + 1 < end) { en = eidx[j + 1]; sn = ei[en]; }
            unsigned int hh = h2u[(size_t)src * 64 + lane];
            float2 av = ((const float2*)(ea + (size_t)e * DD))[lane];
            ax += fmaxf(bflo(hh) + av.x, 0.f);
            ay += fmaxf(bfhi(hh) + av.y, 0.f);
            e = en; src = sn;
        }
        ax += bv.x; ay += bv.y;
        ((float2*)(agg + (size_t)w * DD))[lane] = make_float2(ax, ay);
        sx += ax; qx += ax * ax; sy += ay; qy += ay * ay;
    }
    atomicAdd(&zs[2 * lane], sx);     atomicAdd(&zq[2 * lane], qx);
    atomicAdd(&zs[2 * lane + 1], sy); atomicAdd(&zq[2 * lane + 1], qy);
    __syncthreads();
    if (tid < 128) { atomicAdd(&s1[tid], zs[tid]); atomicAdd(&s1[128 + tid], zq[tid]); }
}

// ---------------- y1 = x + relu(bn1(agg)); fused s2 stats ----------------
__global__ __launch_bounds__(256) void k_y1(const float* __restrict__ x,
                                            const float* __restrict__ agg,
                                            const float* __restrict__ s1,
                                            const float* __restrict__ g,
                                            const float* __restrict__ bb,
                                            float* __restrict__ y1,
                                            float* __restrict__ s2) {
    __shared__ float zs[128], zq[128];
    int tid = threadIdx.x;
    if (tid < 128) { zs[tid] = 0.f; zq[tid] = 0.f; }
    __syncthreads();
    int c0 = (tid & 31) * 4;
    float A[4], C[4], ls[4] = {0,0,0,0}, lq[4] = {0,0,0,0};
    for (int j = 0; j < 4; ++j) {
        int c = c0 + j;
        float m = s1[c] * (1.f / NN);
        float v = s1[128 + c] * (1.f / NN) - m * m;
        float inv = rsqrtf(v + EPS_);
        A[j] = inv * g[c];
        C[j] = bb[c] - m * inv * g[c];
    }
    int step = gridDim.x * 256;
    for (int i = blockIdx.x * 256 + tid; i < NN * 32; i += step) {
        float4 av = ((const float4*)agg)[i];
        float4 xv = ((const float4*)x)[i];
        float4 r;
        r.x = xv.x + fmaxf(av.x * A[0] + C[0], 0.f);
        r.y = xv.y + fmaxf(av.y * A[1] + C[1], 0.f);
        r.z = xv.z + fmaxf(av.z * A[2] + C[2], 0.f);
        r.w = xv.w + fmaxf(av.w * A[3] + C[3], 0.f);
        ((float4*)y1)[i] = r;
        ls[0] += r.x; lq[0] += r.x * r.x;
        ls[1] += r.y; lq[1] += r.y * r.y;
        ls[2] += r.z; lq[2] += r.z * r.z;
        ls[3] += r.w; lq[3] += r.w * r.w;
    }
    for (int j = 0; j < 4; ++j) {
        atomicAdd(&zs[c0 + j], ls[j]);
        atomicAdd(&zq[c0 + j], lq[j]);
    }
    __syncthreads();
    if (tid < 128) { atomicAdd(&s2[tid], zs[tid]); atomicAdd(&s2[128 + tid], zq[tid]); }
}

// ---------------- MFMA FFN: z = y2 + relu(y2@W1^T+b1)@W2^T + b2; fused s3 ----------------
__global__ __launch_bounds__(256) void k_ffn2(const float* __restrict__ y1,
                                              const float* __restrict__ s2,
                                              const float* __restrict__ g2,
                                              const float* __restrict__ bl2,
                                              const __bf16* __restrict__ W1b,
                                              const float* __restrict__ b1,
                                              const __bf16* __restrict__ W2b,
                                              const float* __restrict__ b2f,
                                              float* __restrict__ z,
                                              float* __restrict__ s3) {
    __shared__ __bf16 ys[64 * 128];   // swizzled bf16 y2
    __shared__ __bf16 hs[64 * 256];   // swizzled bf16 hidden
    __shared__ float zs[128], zq[128];
    int tid = threadIdx.x;
    int row0 = blockIdx.x * 64;
    int V = NN - row0; if (V > 64) V = 64;
    if (tid < 128) { zs[tid] = 0.f; zq[tid] = 0.f; }

    {   // phase A: ys = bf16(bnl(y1)), swizzled
        int c0 = (tid & 31) * 4;
        float A[4], C[4];
        for (int j = 0; j < 4; ++j) {
            int c = c0 + j;
            float m = s2[c] * (1.f / NN);
            float v = s2[128 + c] * (1.f / NN) - m * m;
            float inv = rsqrtf(v + EPS_);
            A[j] = inv * g2[c];
            C[j] = bl2[c] - m * inv * g2[c];
        }
        for (int j = 0; j < 8; ++j) {
            int idx = j * 256 + tid;
            int r = idx >> 5;
            float4 v = make_float4(0.f, 0.f, 0.f, 0.f);
            if (r < V) v = ((const float4*)(y1 + (size_t)row0 * DD))[idx];
            bf16x4 bv;
            bv[0] = (__bf16)(v.x * A[0] + C[0]);
            bv[1] = (__bf16)(v.y * A[1] + C[1]);
            bv[2] = (__bf16)(v.z * A[2] + C[2]);
            bv[3] = (__bf16)(v.w * A[3] + C[3]);
            int sw = (((c0 >> 3) ^ (r & 7)) << 3) + (c0 & 7);
            *reinterpret_cast<bf16x4*>(&ys[r * 128 + sw]) = bv;
        }
    }
    __syncthreads();

    int l = tid & 63, w = tid >> 6;
    int m0 = w * 16, lr = l & 15, lk = (l >> 4) * 8;
    int mrow = m0 + lr;

    // GEMM1: hidden = relu(y2 @ W1^T + b1)
    bf16x8 a1[4];
    for (int kk = 0; kk < 4; ++kk) {
        int k = kk * 32 + lk;
        int sw = ((k >> 3) ^ (mrow & 7)) << 3;
        a1[kk] = *reinterpret_cast<const bf16x8*>(&ys[mrow * 128 + sw]);
    }
    for (int nt = 0; nt < 16; ++nt) {
        int f0 = nt * 16;
        f32x4 acc = {0.f, 0.f, 0.f, 0.f};
        for (int kk = 0; kk < 4; ++kk) {
            bf16x8 b = *reinterpret_cast<const bf16x8*>(&W1b[(f0 + lr) * 128 + kk * 32 + lk]);
            acc = __builtin_amdgcn_mfma_f32_16x16x32_bf16(a1[kk], b, acc, 0, 0, 0);
        }
        int f = f0 + lr;
        float bias = b1[f];
#pragma unroll
        for (int r = 0; r < 4; ++r) {
            int m = m0 + (l >> 4) * 4 + r;
            float hv = fmaxf(acc[r] + bias, 0.f);
            hs[m * 256 + (((f >> 3) ^ (m & 7)) << 3) + (f & 7)] = (__bf16)hv;
        }
    }
    // no barrier: each wave reads only its own 16 hidden rows

    // GEMM2: z = y2 + hidden @ W2^T + b2
    bf16x8 a2[8];
    for (int kk = 0; kk < 8; ++kk) {
        int k = kk * 32 + lk;
        int sw = ((k >> 3) ^ (mrow & 7)) << 3;
        a2[kk] = *reinterpret_cast<const bf16x8*>(&hs[mrow * 256 + sw]);
    }
    for (int ot = 0; ot < 8; ++ot) {
        int o0 = ot * 16;
        f32x4 acc = {0.f, 0.f, 0.f, 0.f};
        for (int kk = 0; kk < 8; ++kk) {
            bf16x8 b = *reinterpret_cast<const bf16x8*>(&W2b[(o0 + lr) * 256 + kk * 32 + lk]);
            acc = __builtin_amdgcn_mfma_f32_16x16x32_bf16(a2[kk], b, acc, 0, 0, 0);
        }
        int o = o0 + lr;
        float bias2 = b2f[o];
        float lsum = 0.f, lsq = 0.f;
#pragma unroll
        for (int r = 0; r < 4; ++r) {
            int m = m0 + (l >> 4) * 4 + r;
            float y2v = (float)ys[m * 128 + (((o >> 3) ^ (m & 7)) << 3) + (o & 7)];
            float zv = y2v + acc[r] + bias2;
            if (m < V) {
                z[(size_t)(row0 + m) * DD + o] = zv;
                lsum += zv; lsq += zv * zv;
            }
        }
        atomicAdd(&zs[o], lsum);
        atomicAdd(&zq[o], lsq);
    }
    __syncthreads();
    if (tid < 128) { atomicAdd(&s3[tid], zs[tid]); atomicAdd(&s3[128 + tid], zq[tid]); }
}

// ---------------- out = bn2(z) ----------------
__global__ __launch_bounds__(256) void k_out(const float* __restrict__ zin,
                                             const float* __restrict__ stats,
                                             const float* __restrict__ g,
                                             const float* __restrict__ bb,
                                             float* __restrict__ outp) {
    int tid = threadIdx.x;
    int c0 = (tid & 31) * 4;
    float A[4], C[4];
    for (int j = 0; j < 4; ++j) {
        int c = c0 + j;
        float m = stats[c] * (1.f / NN);
        float v = stats[128 + c] * (1.f / NN) - m * m;
        float inv = rsqrtf(v + EPS_);
        A[j] = inv * g[c];
        C[j] = bb[c] - m * inv * g[c];
    }
    const float4* z4 = (const float4*)zin;
    float4* o4 = (float4*)outp;
    int step = gridDim.x * 256;
    for (int i = blockIdx.x * 256 + tid; i < NN * 32; i += step) {
        float4 zv = z4[i];
        float4 r;
        r.x = zv.x * A[0] + C[0];
        r.y = zv.y * A[1] + C[1];
        r.z = zv.z * A[2] + C[2];
        r.w = zv.w * A[3] + C[3];
        o4[i] = r;
    }
}

extern "C" void kernel_launch(void* const* d_in, const int* in_sizes, int n_in,
                              void* d_out, int out_size, void* d_ws, size_t ws_size,
                              hipStream_t stream) {
    const float* x     = (const float*)d_in[0];
    const float* ea    = (const float*)d_in[1];
    const float* W     = (const float*)d_in[2];
    const float* b     = (const float*)d_in[3];
    const float* bn_g  = (const float*)d_in[4];
    const float* bn_b  = (const float*)d_in[5];
    const float* bnl_g = (const float*)d_in[6];
    const float* bnl_b = (const float*)d_in[7];
    const float* bn2_g = (const float*)d_in[8];
    const float* bn2_b = (const float*)d_in[9];
    const float* W1    = (const float*)d_in[10];
    const float* b1    = (const float*)d_in[11];
    const float* W2    = (const float*)d_in[12];
    const float* b2    = (const float*)d_in[13];
    const int*   ei    = (const int*)d_in[14];
    float* out = (float*)d_out;

    char* base = (char*)d_ws;
    // region A [0, 51.2MB): h2 bf16 (25.6MB) + deg (400KB) + eidx (6.4MB); later z f32
    __bf16* h2  = (__bf16*)base;
    int*   deg  = (int*)(base + 25600000);
    int*   eidx = (int*)(base + 26000000);
    float* z    = (float*)base;
    // region B [51.2MB, 102.4MB): agg f32
    float* agg  = (float*)(base + (size_t)NN * DD * 4);
    // stats + bf16 weights
    float* stats = (float*)(base + (size_t)2 * NN * DD * 4);
    float* s1 = stats;
    float* s2 = stats + 256;
    float* s3 = stats + 512;
    __bf16* Wb  = (__bf16*)(base + (size_t)2 * NN * DD * 4 + 4096);
    __bf16* W1b = Wb + 16384;
    __bf16* W2b = W1b + 32768;

    hipLaunchKernelGGL(k_zero_stats, dim3(1),    dim3(256),  0, stream, stats);
    hipLaunchKernelGGL(k_zero_int,   dim3(391),  dim3(256),  0, stream, deg);
    hipLaunchKernelGGL(k_prepw,      dim3(320),  dim3(256),  0, stream, W, W1, W2, Wb, W1b, W2b);
    hipLaunchKernelGGL(k_gemmx,      dim3(1563), dim3(256),  0, stream, x, Wb, h2);
    hipLaunchKernelGGL(k_hist,       dim3(6250), dim3(256),  0, stream, ei, deg);
    hipLaunchKernelGGL(k_scan,       dim3(1),    dim3(1024), 0, stream, deg);
    hipLaunchKernelGGL(k_fill,       dim3(6250), dim3(256),  0, stream, ei, deg, eidx);
    hipLaunchKernelGGL(k_gather,     dim3(2048), dim3(256),  0, stream,
                       (const unsigned int*)h2, ea, ei, deg, eidx, b, agg, s1);
    hipLaunchKernelGGL(k_y1,         dim3(2048), dim3(256),  0, stream, x, agg, s1, bn_g, bn_b, out, s2);
    hipLaunchKernelGGL(k_ffn2,       dim3(1563), dim3(256),  0, stream, out, s2, bnl_g, bnl_b,
                       W1b, b1, W2b, b2, z, s3);
    hipLaunchKernelGGL(k_out,        dim3(2048), dim3(256),  0, stream, z, s3, bn2_g, bn2_b, out);
}

// Round 4
// 951.307 us; speedup vs baseline: 3.6035x; 1.0427x over previous
//
#include <hip/hip_runtime.h>
#include <hip/hip_bf16.h>

#define NN 100000
#define NE 1600000
#define DD 128
#define FF 256
static constexpr float EPS_ = 1e-5f;

typedef __bf16 bf16x4 __attribute__((ext_vector_type(4)));
typedef __bf16 bf16x8 __attribute__((ext_vector_type(8)));
typedef float  f32x4  __attribute__((ext_vector_type(4)));

__device__ inline float bflo(unsigned int u) { return __uint_as_float(u << 16); }
__device__ inline float bfhi(unsigned int u) { return __uint_as_float(u & 0xFFFF0000u); }

__device__ inline unsigned pack_bf16x2(float x, float y) {
    __hip_bfloat162 t;
    t.x = __float2bfloat16(x);
    t.y = __float2bfloat16(y);
    return *reinterpret_cast<unsigned*>(&t);
}
__device__ inline void bf8_to_f(uint4 u, float* f) {
    f[0] = bflo(u.x); f[1] = bfhi(u.x);
    f[2] = bflo(u.y); f[3] = bfhi(u.y);
    f[4] = bflo(u.z); f[5] = bfhi(u.z);
    f[6] = bflo(u.w); f[7] = bfhi(u.w);
}
__device__ inline uint4 f_to_bf8(const float* f) {
    uint4 u;
    u.x = pack_bf16x2(f[0], f[1]);
    u.y = pack_bf16x2(f[2], f[3]);
    u.z = pack_bf16x2(f[4], f[5]);
    u.w = pack_bf16x2(f[6], f[7]);
    return u;
}
__device__ inline float2 ntload2(const float* p) {
    double d = __builtin_nontemporal_load((const double*)p);
    return *reinterpret_cast<float2*>(&d);
}

// ---------------- zero the 6x128 stats accumulators ----------------
__global__ __launch_bounds__(256) void k_zero_stats(float* __restrict__ stats) {
    int t = threadIdx.x;
    for (int i = t; i < 768; i += 256) stats[i] = 0.f;
}

// ---------------- zero deg[N] ----------------
__global__ __launch_bounds__(256) void k_zero_int(int* __restrict__ p) {
    int i = blockIdx.x * 256 + threadIdx.x;
    if (i < NN) p[i] = 0;
}

// ---------------- fp32 -> bf16 weight copies ----------------
__global__ __launch_bounds__(256) void k_prepw(const float* __restrict__ W,
                                               const float* __restrict__ W1,
                                               const float* __restrict__ W2,
                                               __bf16* __restrict__ Wb,
                                               __bf16* __restrict__ W1b,
                                               __bf16* __restrict__ W2b) {
    int i = blockIdx.x * 256 + threadIdx.x;
    if (i < 16384) Wb[i] = (__bf16)W[i];
    if (i >= 16384 && i < 49152) W1b[i - 16384] = (__bf16)W1[i - 16384];
    if (i >= 49152 && i < 81920) W2b[i - 49152] = (__bf16)W2[i - 49152];
}

// ---------------- h = x @ W^T -> bf16, via MFMA ----------------
__global__ __launch_bounds__(256) void k_gemmx(const float* __restrict__ x,
                                               const __bf16* __restrict__ Wb,
                                               __bf16* __restrict__ h2) {
    __shared__ __bf16 xs[64 * 128];
    int tid = threadIdx.x;
    int row0 = blockIdx.x * 64;
    int V = NN - row0; if (V > 64) V = 64;

    {   // fill xs (coalesced float4 reads, swizzled bf16 stores)
        int c0 = (tid & 31) * 4;
        for (int j = 0; j < 8; ++j) {
            int idx = j * 256 + tid;
            int r = idx >> 5;
            float4 v = make_float4(0.f, 0.f, 0.f, 0.f);
            if (r < V) v = ((const float4*)(x + (size_t)row0 * DD))[idx];
            bf16x4 bv; bv[0] = (__bf16)v.x; bv[1] = (__bf16)v.y; bv[2] = (__bf16)v.z; bv[3] = (__bf16)v.w;
            int sw = (((c0 >> 3) ^ (r & 7)) << 3) + (c0 & 7);
            *reinterpret_cast<bf16x4*>(&xs[r * 128 + sw]) = bv;
        }
    }
    __syncthreads();

    int l = tid & 63, w = tid >> 6;
    int m0 = w * 16, lr = l & 15, lk = (l >> 4) * 8;
    int mrow = m0 + lr;

    bf16x8 a[4];
    for (int kk = 0; kk < 4; ++kk) {
        int k = kk * 32 + lk;
        int sw = ((k >> 3) ^ (mrow & 7)) << 3;
        a[kk] = *reinterpret_cast<const bf16x8*>(&xs[mrow * 128 + sw]);
    }
    for (int nt = 0; nt < 8; ++nt) {
        int n0 = nt * 16;
        f32x4 acc = {0.f, 0.f, 0.f, 0.f};
        for (int kk = 0; kk < 4; ++kk) {
            bf16x8 b = *reinterpret_cast<const bf16x8*>(&Wb[(n0 + lr) * 128 + kk * 32 + lk]);
            acc = __builtin_amdgcn_mfma_f32_16x16x32_bf16(a[kk], b, acc, 0, 0, 0);
        }
        int n = n0 + lr;
#pragma unroll
        for (int r = 0; r < 4; ++r) {
            int m = m0 + (l >> 4) * 4 + r;
            xs[m * 128 + n] = (__bf16)acc[r];   // unswizzled, own rows only
        }
    }
    for (int i = 0; i < 8; ++i) {
        int j = i * 64 + l;
        int rl = j >> 5;
        int c4 = j & 31;
        int m = m0 + rl;
        if (row0 + m < NN) {
            bf16x4 v = *reinterpret_cast<const bf16x4*>(&xs[m * 128 + c4 * 4]);
            *reinterpret_cast<bf16x4*>(&h2[(size_t)(row0 + m) * 128 + c4 * 4]) = v;
        }
    }
}

// ---------------- deg histogram over dst ----------------
__global__ __launch_bounds__(256) void k_hist(const int* __restrict__ ei,
                                              int* __restrict__ deg) {
    int e = blockIdx.x * 256 + threadIdx.x;
    if (e < NE) atomicAdd(&deg[ei[NE + e]], 1);
}

// ---------------- in-place exclusive scan of deg[N] (single block) ----------------
__global__ __launch_bounds__(1024) void k_scan(int* __restrict__ p) {
    __shared__ int part[1024];
    int t = threadIdx.x;
    const int CH = (NN + 1023) / 1024;
    int i0 = t * CH;
    int iend = i0 + CH; if (iend > NN) iend = NN; if (i0 > NN) i0 = NN;
    int s = 0;
    for (int i = i0; i < iend; ++i) s += p[i];
    part[t] = s;
    __syncthreads();
    for (int d = 1; d < 1024; d <<= 1) {
        int add = (t >= d) ? part[t - d] : 0;
        __syncthreads();
        part[t] += add;
        __syncthreads();
    }
    int off = (t == 0) ? 0 : part[t - 1];
    for (int i = i0; i < iend; ++i) {
        int v = p[i];
        p[i] = off;
        off += v;
    }
}

// ---------------- fill pair[pos]={src,e} sorted by dst ----------------
__global__ __launch_bounds__(256) void k_fill(const int* __restrict__ ei,
                                              int* __restrict__ ptr,
                                              int2* __restrict__ pair) {
    int e = blockIdx.x * 256 + threadIdx.x;
    if (e >= NE) return;
    int s = ei[e];
    int d = ei[NE + e];
    int pos = atomicAdd(&ptr[d], 1);
    pair[pos] = make_int2(s, e);
}

// ---------------- gather: agg[i] = b + sum relu(h[src]+ea[e]) -> bf16; fused s1 ----------------
__global__ __launch_bounds__(256) void k_gather(const unsigned int* __restrict__ h2u,
                                                const float* __restrict__ ea,
                                                const int2* __restrict__ pair,
                                                const int* __restrict__ ptr,
                                                const float* __restrict__ bias,
                                                unsigned int* __restrict__ aggb,
                                                float* __restrict__ s1) {
    __shared__ float zs[128], zq[128];
    int tid = threadIdx.x;
    if (tid < 128) { zs[tid] = 0.f; zq[tid] = 0.f; }
    __syncthreads();
    int lane = tid & 63;
    int wglob = blockIdx.x * 4 + (tid >> 6);
    int nwaves = gridDim.x * 4;
    float2 bv = ((const float2*)bias)[lane];
    float sx = 0.f, qx = 0.f, sy = 0.f, qy = 0.f;
    for (int w = wglob; w < NN; w += nwaves) {
        int beg = (w == 0) ? 0 : ptr[w - 1];
        int end = ptr[w];
        float ax = 0.f, ay = 0.f;
        // 2-deep software pipeline over edges
        unsigned ha = 0, hb = 0;
        float2 aa = make_float2(0.f, 0.f), ab = make_float2(0.f, 0.f);
        if (beg < end) {
            int2 p = pair[beg];
            ha = h2u[(size_t)p.x * 64 + lane];
            aa = ntload2(ea + (size_t)p.y * DD + 2 * lane);
        }
        if (beg + 1 < end) {
            int2 p = pair[beg + 1];
            hb = h2u[(size_t)p.x * 64 + lane];
            ab = ntload2(ea + (size_t)p.y * DD + 2 * lane);
        }
        for (int j = beg; j < end; ++j) {
            unsigned hc = 0;
            float2 ac = make_float2(0.f, 0.f);
            if (j + 2 < end) {
                int2 p = pair[j + 2];
                hc = h2u[(size_t)p.x * 64 + lane];
                ac = ntload2(ea + (size_t)p.y * DD + 2 * lane);
            }
            ax += fmaxf(bflo(ha) + aa.x, 0.f);
            ay += fmaxf(bfhi(ha) + aa.y, 0.f);
            ha = hb; aa = ab;
            hb = hc; ab = ac;
        }
        ax += bv.x; ay += bv.y;
        aggb[(size_t)w * 64 + lane] = pack_bf16x2(ax, ay);
        sx += ax; qx += ax * ax; sy += ay; qy += ay * ay;
    }
    atomicAdd(&zs[2 * lane], sx);     atomicAdd(&zq[2 * lane], qx);
    atomicAdd(&zs[2 * lane + 1], sy); atomicAdd(&zq[2 * lane + 1], qy);
    __syncthreads();
    if (tid < 128) { atomicAdd(&s1[tid], zs[tid]); atomicAdd(&s1[128 + tid], zq[tid]); }
}

// ---------------- y1 = x + relu(bn1(agg)) -> bf16; fused s2 ----------------
__global__ __launch_bounds__(256) void k_y1(const float* __restrict__ x,
                                            const uint4* __restrict__ aggb,
                                            const float* __restrict__ s1,
                                            const float* __restrict__ g,
                                            const float* __restrict__ bb,
                                            uint4* __restrict__ y1b,
                                            float* __restrict__ s2) {
    __shared__ float zs[128], zq[128];
    int tid = threadIdx.x;
    if (tid < 128) { zs[tid] = 0.f; zq[tid] = 0.f; }
    __syncthreads();
    int c0 = (tid & 15) * 8;
    float A[8], C[8], ls[8] = {0,0,0,0,0,0,0,0}, lq[8] = {0,0,0,0,0,0,0,0};
#pragma unroll
    for (int j = 0; j < 8; ++j) {
        int c = c0 + j;
        float m = s1[c] * (1.f / NN);
        float v = s1[128 + c] * (1.f / NN) - m * m;
        float inv = rsqrtf(v + EPS_);
        A[j] = inv * g[c];
        C[j] = bb[c] - m * inv * g[c];
    }
    int step = gridDim.x * 256;
    for (int i = blockIdx.x * 256 + tid; i < NN * 16; i += step) {
        float av[8];
        bf8_to_f(aggb[i], av);
        float4 x0 = ((const float4*)x)[2 * i];
        float4 x1 = ((const float4*)x)[2 * i + 1];
        float xv[8] = {x0.x, x0.y, x0.z, x0.w, x1.x, x1.y, x1.z, x1.w};
        float r[8];
#pragma unroll
        for (int j = 0; j < 8; ++j) {
            r[j] = xv[j] + fmaxf(av[j] * A[j] + C[j], 0.f);
            ls[j] += r[j]; lq[j] += r[j] * r[j];
        }
        y1b[i] = f_to_bf8(r);
    }
#pragma unroll
    for (int j = 0; j < 8; ++j) {
        atomicAdd(&zs[c0 + j], ls[j]);
        atomicAdd(&zq[c0 + j], lq[j]);
    }
    __syncthreads();
    if (tid < 128) { atomicAdd(&s2[tid], zs[tid]); atomicAdd(&s2[128 + tid], zq[tid]); }
}

// ---------------- MFMA FFN: z = y2 + relu(y2@W1^T+b1)@W2^T + b2 -> bf16; fused s3 ----------------
__global__ __launch_bounds__(256) void k_ffn2(const uint4* __restrict__ y1b,
                                              const float* __restrict__ s2,
                                              const float* __restrict__ g2,
                                              const float* __restrict__ bl2,
                                              const __bf16* __restrict__ W1b,
                                              const float* __restrict__ b1,
                                              const __bf16* __restrict__ W2b,
                                              const float* __restrict__ b2f,
                                              __bf16* __restrict__ z,
                                              float* __restrict__ s3) {
    __shared__ __bf16 ys[64 * 128];   // swizzled bf16 y2
    __shared__ __bf16 hs[64 * 256];   // swizzled bf16 hidden
    __shared__ float zs[128], zq[128];
    int tid = threadIdx.x;
    int row0 = blockIdx.x * 64;
    int V = NN - row0; if (V > 64) V = 64;
    if (tid < 128) { zs[tid] = 0.f; zq[tid] = 0.f; }

    {   // phase A: ys = bf16(bnl(y1)), swizzled
        int chunk = tid & 15;
        int c0 = chunk * 8;
        float A[8], C[8];
#pragma unroll
        for (int j = 0; j < 8; ++j) {
            int c = c0 + j;
            float m = s2[c] * (1.f / NN);
            float v = s2[128 + c] * (1.f / NN) - m * m;
            float inv = rsqrtf(v + EPS_);
            A[j] = inv * g2[c];
            C[j] = bl2[c] - m * inv * g2[c];
        }
        const uint4* yt = y1b + (size_t)row0 * 16;
        for (int j = 0; j < 4; ++j) {
            int idx = j * 256 + tid;
            int r = idx >> 4;
            uint4 u = make_uint4(0, 0, 0, 0);
            if (r < V) u = yt[idx];
            float f[8];
            bf8_to_f(u, f);
            float o[8];
#pragma unroll
            for (int q = 0; q < 8; ++q) o[q] = f[q] * A[q] + C[q];
            uint4 pk = f_to_bf8(o);
            *reinterpret_cast<uint4*>(&ys[r * 128 + ((chunk ^ (r & 7)) << 3)]) = pk;
        }
    }
    __syncthreads();

    int l = tid & 63, w = tid >> 6;
    int m0 = w * 16, lr = l & 15, lk = (l >> 4) * 8;
    int mrow = m0 + lr;

    // GEMM1: hidden = relu(y2 @ W1^T + b1)
    bf16x8 a1[4];
    for (int kk = 0; kk < 4; ++kk) {
        int k = kk * 32 + lk;
        int sw = ((k >> 3) ^ (mrow & 7)) << 3;
        a1[kk] = *reinterpret_cast<const bf16x8*>(&ys[mrow * 128 + sw]);
    }
    for (int nt = 0; nt < 16; ++nt) {
        int f0 = nt * 16;
        f32x4 acc = {0.f, 0.f, 0.f, 0.f};
        for (int kk = 0; kk < 4; ++kk) {
            bf16x8 b = *reinterpret_cast<const bf16x8*>(&W1b[(f0 + lr) * 128 + kk * 32 + lk]);
            acc = __builtin_amdgcn_mfma_f32_16x16x32_bf16(a1[kk], b, acc, 0, 0, 0);
        }
        int f = f0 + lr;
        float bias = b1[f];
#pragma unroll
        for (int r = 0; r < 4; ++r) {
            int m = m0 + (l >> 4) * 4 + r;
            float hv = fmaxf(acc[r] + bias, 0.f);
            hs[m * 256 + (((f >> 3) ^ (m & 7)) << 3) + (f & 7)] = (__bf16)hv;
        }
    }
    // no barrier: each wave reads only its own 16 hidden rows

    // GEMM2: z = y2 + hidden @ W2^T + b2
    bf16x8 a2[8];
    for (int kk = 0; kk < 8; ++kk) {
        int k = kk * 32 + lk;
        int sw = ((k >> 3) ^ (mrow & 7)) << 3;
        a2[kk] = *reinterpret_cast<const bf16x8*>(&hs[mrow * 256 + sw]);
    }
    for (int ot = 0; ot < 8; ++ot) {
        int o0 = ot * 16;
        f32x4 acc = {0.f, 0.f, 0.f, 0.f};
        for (int kk = 0; kk < 8; ++kk) {
            bf16x8 b = *reinterpret_cast<const bf16x8*>(&W2b[(o0 + lr) * 256 + kk * 32 + lk]);
            acc = __builtin_amdgcn_mfma_f32_16x16x32_bf16(a2[kk], b, acc, 0, 0, 0);
        }
        int o = o0 + lr;
        float bias2 = b2f[o];
        float lsum = 0.f, lsq = 0.f;
#pragma unroll
        for (int r = 0; r < 4; ++r) {
            int m = m0 + (l >> 4) * 4 + r;
            float y2v = (float)ys[m * 128 + (((o >> 3) ^ (m & 7)) << 3) + (o & 7)];
            float zv = y2v + acc[r] + bias2;
            if (m < V) {
                z[(size_t)(row0 + m) * DD + o] = (__bf16)zv;
                lsum += zv; lsq += zv * zv;
            }
        }
        atomicAdd(&zs[o], lsum);
        atomicAdd(&zq[o], lsq);
    }
    __syncthreads();
    if (tid < 128) { atomicAdd(&s3[tid], zs[tid]); atomicAdd(&s3[128 + tid], zq[tid]); }
}

// ---------------- out = bn2(z) ----------------
__global__ __launch_bounds__(256) void k_out(const uint4* __restrict__ zb,
                                             const float* __restrict__ stats,
                                             const float* __restrict__ g,
                                             const float* __restrict__ bb,
                                             float* __restrict__ outp) {
    int tid = threadIdx.x;
    int c0 = (tid & 15) * 8;
    float A[8], C[8];
#pragma unroll
    for (int j = 0; j < 8; ++j) {
        int c = c0 + j;
        float m = stats[c] * (1.f / NN);
        float v = stats[128 + c] * (1.f / NN) - m * m;
        float inv = rsqrtf(v + EPS_);
        A[j] = inv * g[c];
        C[j] = bb[c] - m * inv * g[c];
    }
    float4* o4 = (float4*)outp;
    int step = gridDim.x * 256;
    for (int i = blockIdx.x * 256 + tid; i < NN * 16; i += step) {
        float f[8];
        bf8_to_f(zb[i], f);
        float4 r0, r1;
        r0.x = f[0] * A[0] + C[0]; r0.y = f[1] * A[1] + C[1];
        r0.z = f[2] * A[2] + C[2]; r0.w = f[3] * A[3] + C[3];
        r1.x = f[4] * A[4] + C[4]; r1.y = f[5] * A[5] + C[5];
        r1.z = f[6] * A[6] + C[6]; r1.w = f[7] * A[7] + C[7];
        o4[2 * i] = r0;
        o4[2 * i + 1] = r1;
    }
}

extern "C" void kernel_launch(void* const* d_in, const int* in_sizes, int n_in,
                              void* d_out, int out_size, void* d_ws, size_t ws_size,
                              hipStream_t stream) {
    const float* x     = (const float*)d_in[0];
    const float* ea    = (const float*)d_in[1];
    const float* W     = (const float*)d_in[2];
    const float* b     = (const float*)d_in[3];
    const float* bn_g  = (const float*)d_in[4];
    const float* bn_b  = (const float*)d_in[5];
    const float* bnl_g = (const float*)d_in[6];
    const float* bnl_b = (const float*)d_in[7];
    const float* bn2_g = (const float*)d_in[8];
    const float* bn2_b = (const float*)d_in[9];
    const float* W1    = (const float*)d_in[10];
    const float* b1    = (const float*)d_in[11];
    const float* W2    = (const float*)d_in[12];
    const float* b2    = (const float*)d_in[13];
    const int*   ei    = (const int*)d_in[14];
    float* out = (float*)d_out;

    char* base = (char*)d_ws;
    // [0, 25.6M): h2 bf16; later z bf16 (h2/pair dead once ffn2 runs)
    __bf16* h2   = (__bf16*)base;
    __bf16* z    = (__bf16*)base;
    int*    deg  = (int*)(base + 25600000);       // 400 KB
    int2*   pair = (int2*)(base + 26000000);      // 12.8 MB -> ends 38.8 MB
    // [51.2M, 76.8M): agg bf16 ; [76.8M, 102.4M): y1 bf16
    unsigned int* aggb = (unsigned int*)(base + 51200000);
    uint4*        y1b  = (uint4*)(base + 76800000);
    float* stats = (float*)(base + 102400000);
    float* s1 = stats;
    float* s2 = stats + 256;
    float* s3 = stats + 512;
    __bf16* Wb  = (__bf16*)(base + 102404096);
    __bf16* W1b = Wb + 16384;
    __bf16* W2b = W1b + 32768;

    hipLaunchKernelGGL(k_zero_stats, dim3(1),    dim3(256),  0, stream, stats);
    hipLaunchKernelGGL(k_zero_int,   dim3(391),  dim3(256),  0, stream, deg);
    hipLaunchKernelGGL(k_prepw,      dim3(320),  dim3(256),  0, stream, W, W1, W2, Wb, W1b, W2b);
    hipLaunchKernelGGL(k_gemmx,      dim3(1563), dim3(256),  0, stream, x, Wb, h2);
    hipLaunchKernelGGL(k_hist,       dim3(6250), dim3(256),  0, stream, ei, deg);
    hipLaunchKernelGGL(k_scan,       dim3(1),    dim3(1024), 0, stream, deg);
    hipLaunchKernelGGL(k_fill,       dim3(6250), dim3(256),  0, stream, ei, deg, pair);
    hipLaunchKernelGGL(k_gather,     dim3(6250), dim3(256),  0, stream,
                       (const unsigned int*)h2, ea, pair, deg, b, aggb, s1);
    hipLaunchKernelGGL(k_y1,         dim3(2048), dim3(256),  0, stream,
                       x, (const uint4*)aggb, s1, bn_g, bn_b, y1b, s2);
    hipLaunchKernelGGL(k_ffn2,       dim3(1563), dim3(256),  0, stream, y1b, s2, bnl_g, bnl_b,
                       W1b, b1, W2b, b2, z, s3);
    hipLaunchKernelGGL(k_out,        dim3(2048), dim3(256),  0, stream,
                       (const uint4*)z, s3, bn2_g, bn2_b, out);
}

// Round 5
// 727.290 us; speedup vs baseline: 4.7134x; 1.3080x over previous
//
#include <hip/hip_runtime.h>
#include <hip/hip_bf16.h>

#define NN 100000
#define NE 1600000
#define DD 128
#define FF 256
#define NSTRIPE 16
static constexpr float EPS_ = 1e-5f;

typedef __bf16 bf16x4 __attribute__((ext_vector_type(4)));
typedef __bf16 bf16x8 __attribute__((ext_vector_type(8)));
typedef float  f32x4  __attribute__((ext_vector_type(4)));

__device__ inline float bflo(unsigned int u) { return __uint_as_float(u << 16); }
__device__ inline float bfhi(unsigned int u) { return __uint_as_float(u & 0xFFFF0000u); }

__device__ inline unsigned pack_bf16x2(float x, float y) {
    __hip_bfloat162 t;
    t.x = __float2bfloat16(x);
    t.y = __float2bfloat16(y);
    return *reinterpret_cast<unsigned*>(&t);
}
__device__ inline void bf8_to_f(uint4 u, float* f) {
    f[0] = bflo(u.x); f[1] = bfhi(u.x);
    f[2] = bflo(u.y); f[3] = bfhi(u.y);
    f[4] = bflo(u.z); f[5] = bfhi(u.z);
    f[6] = bflo(u.w); f[7] = bfhi(u.w);
}
__device__ inline uint4 f_to_bf8(const float* f) {
    uint4 u;
    u.x = pack_bf16x2(f[0], f[1]);
    u.y = pack_bf16x2(f[2], f[3]);
    u.z = pack_bf16x2(f[4], f[5]);
    u.w = pack_bf16x2(f[6], f[7]);
    return u;
}
__device__ inline float2 ntload2(const float* p) {
    double d = __builtin_nontemporal_load((const double*)p);
    return *reinterpret_cast<float2*>(&d);
}
// sum a column over the 16 stat stripes
__device__ inline float stripe_sum(const float* s, int idx) {
    float r = 0.f;
#pragma unroll
    for (int st = 0; st < NSTRIPE; ++st) r += s[st * 256 + idx];
    return r;
}

// ---------------- init: zero deg + zero stat stripes + cvt weights ----------------
__global__ __launch_bounds__(256) void k_init(const float* __restrict__ W,
                                              const float* __restrict__ W1,
                                              const float* __restrict__ W2,
                                              __bf16* __restrict__ Wb,
                                              __bf16* __restrict__ W1b,
                                              __bf16* __restrict__ W2b,
                                              int* __restrict__ deg,
                                              float* __restrict__ stripes) {
    int i = blockIdx.x * 256 + threadIdx.x;
    if (i < NN) deg[i] = 0;
    if (i < 3 * NSTRIPE * 256) stripes[i] = 0.f;
    if (i < 16384) Wb[i] = (__bf16)W[i];
    if (i < 32768) W1b[i] = (__bf16)W1[i];
    if (i < 32768) W2b[i] = (__bf16)W2[i];
}

// ---------------- h = x @ W^T -> bf16, via MFMA ----------------
__global__ __launch_bounds__(256) void k_gemmx(const float* __restrict__ x,
                                               const __bf16* __restrict__ Wb,
                                               __bf16* __restrict__ h2) {
    __shared__ __bf16 xs[64 * 128];
    int tid = threadIdx.x;
    int row0 = blockIdx.x * 64;
    int V = NN - row0; if (V > 64) V = 64;

    {   // fill xs (coalesced float4 reads, swizzled bf16 stores)
        int c0 = (tid & 31) * 4;
        for (int j = 0; j < 8; ++j) {
            int idx = j * 256 + tid;
            int r = idx >> 5;
            float4 v = make_float4(0.f, 0.f, 0.f, 0.f);
            if (r < V) v = ((const float4*)(x + (size_t)row0 * DD))[idx];
            bf16x4 bv; bv[0] = (__bf16)v.x; bv[1] = (__bf16)v.y; bv[2] = (__bf16)v.z; bv[3] = (__bf16)v.w;
            int sw = (((c0 >> 3) ^ (r & 7)) << 3) + (c0 & 7);
            *reinterpret_cast<bf16x4*>(&xs[r * 128 + sw]) = bv;
        }
    }
    __syncthreads();

    int l = tid & 63, w = tid >> 6;
    int m0 = w * 16, lr = l & 15, lk = (l >> 4) * 8;
    int mrow = m0 + lr;

    bf16x8 a[4];
    for (int kk = 0; kk < 4; ++kk) {
        int k = kk * 32 + lk;
        int sw = ((k >> 3) ^ (mrow & 7)) << 3;
        a[kk] = *reinterpret_cast<const bf16x8*>(&xs[mrow * 128 + sw]);
    }
    for (int nt = 0; nt < 8; ++nt) {
        int n0 = nt * 16;
        f32x4 acc = {0.f, 0.f, 0.f, 0.f};
        for (int kk = 0; kk < 4; ++kk) {
            bf16x8 b = *reinterpret_cast<const bf16x8*>(&Wb[(n0 + lr) * 128 + kk * 32 + lk]);
            acc = __builtin_amdgcn_mfma_f32_16x16x32_bf16(a[kk], b, acc, 0, 0, 0);
        }
        int n = n0 + lr;
#pragma unroll
        for (int r = 0; r < 4; ++r) {
            int m = m0 + (l >> 4) * 4 + r;
            xs[m * 128 + n] = (__bf16)acc[r];   // unswizzled, own rows only
        }
    }
    for (int i = 0; i < 8; ++i) {
        int j = i * 64 + l;
        int rl = j >> 5;
        int c4 = j & 31;
        int m = m0 + rl;
        if (row0 + m < NN) {
            bf16x4 v = *reinterpret_cast<const bf16x4*>(&xs[m * 128 + c4 * 4]);
            *reinterpret_cast<bf16x4*>(&h2[(size_t)(row0 + m) * 128 + c4 * 4]) = v;
        }
    }
}

// ---------------- deg histogram over dst ----------------
__global__ __launch_bounds__(256) void k_hist(const int* __restrict__ ei,
                                              int* __restrict__ deg) {
    int e = blockIdx.x * 256 + threadIdx.x;
    if (e < NE) atomicAdd(&deg[ei[NE + e]], 1);
}

// ---------------- scan stage A: per-1024-chunk block sums ----------------
__global__ __launch_bounds__(256) void k_scanA(const int* __restrict__ p,
                                               int* __restrict__ bsum) {
    __shared__ int red[256];
    int b = blockIdx.x, tid = threadIdx.x;
    int base = b * 1024;
    int s = 0;
    for (int i = tid; i < 1024; i += 256) {
        int idx = base + i;
        s += (idx < NN) ? p[idx] : 0;
    }
    red[tid] = s;
    __syncthreads();
    for (int d = 128; d > 0; d >>= 1) {
        if (tid < d) red[tid] += red[tid + d];
        __syncthreads();
    }
    if (tid == 0) bsum[b] = red[0];
}

// ---------------- scan stage B: in-place exclusive scan ----------------
__global__ __launch_bounds__(256) void k_scanB(int* __restrict__ p,
                                               const int* __restrict__ bsum) {
    __shared__ int part[256];
    __shared__ int boff_sh;
    int b = blockIdx.x, tid = threadIdx.x;
    if (tid == 0) {
        int s = 0;
        for (int i = 0; i < b; ++i) s += bsum[i];
        boff_sh = s;
    }
    int base = b * 1024 + tid * 4;
    int4 v = make_int4(0, 0, 0, 0);
    bool full = (base + 3 < NN);
    if (full) v = *(const int4*)(p + base);
    else {
        if (base + 0 < NN) v.x = p[base + 0];
        if (base + 1 < NN) v.y = p[base + 1];
        if (base + 2 < NN) v.z = p[base + 2];
        if (base + 3 < NN) v.w = p[base + 3];
    }
    int tsum = v.x + v.y + v.z + v.w;
    part[tid] = tsum;
    __syncthreads();
    for (int d = 1; d < 256; d <<= 1) {
        int add = (tid >= d) ? part[tid - d] : 0;
        __syncthreads();
        part[tid] += add;
        __syncthreads();
    }
    int texcl = part[tid] - tsum + boff_sh;
    int4 o;
    o.x = texcl;
    o.y = texcl + v.x;
    o.z = texcl + v.x + v.y;
    o.w = texcl + v.x + v.y + v.z;
    if (full) *(int4*)(p + base) = o;
    else {
        if (base + 0 < NN) p[base + 0] = o.x;
        if (base + 1 < NN) p[base + 1] = o.y;
        if (base + 2 < NN) p[base + 2] = o.z;
        if (base + 3 < NN) p[base + 3] = o.w;
    }
}

// ---------------- fill pair[pos]={src,e} sorted by dst ----------------
__global__ __launch_bounds__(256) void k_fill(const int* __restrict__ ei,
                                              int* __restrict__ ptr,
                                              int2* __restrict__ pair) {
    int e = blockIdx.x * 256 + threadIdx.x;
    if (e >= NE) return;
    int s = ei[e];
    int d = ei[NE + e];
    int pos = atomicAdd(&ptr[d], 1);
    pair[pos] = make_int2(s, e);
}

// ---------------- gather: agg = b + sum relu(h[src]+ea[e]) -> bf16; striped s1 ----------------
// one wave per node (grid-stride), 2 cols/lane, 4-deep static software pipeline
__global__ __launch_bounds__(256) void k_gather(const unsigned int* __restrict__ h2u,
                                                const float* __restrict__ ea,
                                                const int2* __restrict__ pair,
                                                const int* __restrict__ ptr,
                                                const float* __restrict__ bias,
                                                unsigned int* __restrict__ aggb,
                                                float* __restrict__ s1) {
    __shared__ float zsum[128], zsq[128];
    int tid = threadIdx.x;
    if (tid < 128) { zsum[tid] = 0.f; zsq[tid] = 0.f; }
    __syncthreads();
    int lane = tid & 63;
    int wid = blockIdx.x * 4 + (tid >> 6);
    int nw = gridDim.x * 4;
    float2 bv = ((const float2*)bias)[lane];
    float sx = 0.f, qx = 0.f, sy = 0.f, qy = 0.f;

#define ISSUE(H, A, idx)  { int2 p = pair[idx]; \
                            H = h2u[(size_t)p.x * 64 + lane]; \
                            A = ntload2(ea + (size_t)p.y * DD + 2 * lane); }
#define CONSUME(H, A)     { ax += fmaxf(bflo(H) + A.x, 0.f); \
                            ay += fmaxf(bfhi(H) + A.y, 0.f); }

    for (int w = wid; w < NN; w += nw) {
        int beg = (w == 0) ? 0 : ptr[w - 1];
        int end = ptr[w];
        float ax = 0.f, ay = 0.f;
        unsigned H0 = 0, H1 = 0, H2 = 0, H3 = 0;
        float2 A0, A1, A2, A3;
        A0 = A1 = A2 = A3 = make_float2(0.f, 0.f);
        if (beg + 0 < end) ISSUE(H0, A0, beg + 0);
        if (beg + 1 < end) ISSUE(H1, A1, beg + 1);
        if (beg + 2 < end) ISSUE(H2, A2, beg + 2);
        if (beg + 3 < end) ISSUE(H3, A3, beg + 3);
        for (int j = beg; j < end; j += 4) {
            if (j + 0 < end) { CONSUME(H0, A0); if (j + 4 < end) ISSUE(H0, A0, j + 4); }
            if (j + 1 < end) { CONSUME(H1, A1); if (j + 5 < end) ISSUE(H1, A1, j + 5); }
            if (j + 2 < end) { CONSUME(H2, A2); if (j + 6 < end) ISSUE(H2, A2, j + 6); }
            if (j + 3 < end) { CONSUME(H3, A3); if (j + 7 < end) ISSUE(H3, A3, j + 7); }
        }
        ax += bv.x; ay += bv.y;
        aggb[(size_t)w * 64 + lane] = pack_bf16x2(ax, ay);
        sx += ax; qx += ax * ax; sy += ay; qy += ay * ay;
    }
#undef ISSUE
#undef CONSUME
    atomicAdd(&zsum[2 * lane], sx);     atomicAdd(&zsq[2 * lane], qx);
    atomicAdd(&zsum[2 * lane + 1], sy); atomicAdd(&zsq[2 * lane + 1], qy);
    __syncthreads();
    int st = (blockIdx.x & (NSTRIPE - 1)) * 256;
    if (tid < 128) {
        atomicAdd(&s1[st + tid], zsum[tid]);
        atomicAdd(&s1[st + 128 + tid], zsq[tid]);
    }
}

// ---------------- y1 = x + relu(bn1(agg)) -> bf16; striped s2 ----------------
__global__ __launch_bounds__(256) void k_y1(const float* __restrict__ x,
                                            const uint4* __restrict__ aggb,
                                            const float* __restrict__ s1,
                                            const float* __restrict__ g,
                                            const float* __restrict__ bb,
                                            uint4* __restrict__ y1b,
                                            float* __restrict__ s2) {
    __shared__ float zs[128], zq[128];
    int tid = threadIdx.x;
    if (tid < 128) { zs[tid] = 0.f; zq[tid] = 0.f; }
    __syncthreads();
    int c0 = (tid & 15) * 8;
    float A[8], C[8], ls[8] = {0,0,0,0,0,0,0,0}, lq[8] = {0,0,0,0,0,0,0,0};
#pragma unroll
    for (int j = 0; j < 8; ++j) {
        int c = c0 + j;
        float m = stripe_sum(s1, c) * (1.f / NN);
        float v = stripe_sum(s1, 128 + c) * (1.f / NN) - m * m;
        float inv = rsqrtf(v + EPS_);
        A[j] = inv * g[c];
        C[j] = bb[c] - m * inv * g[c];
    }
    int step = gridDim.x * 256;
    for (int i = blockIdx.x * 256 + tid; i < NN * 16; i += step) {
        float av[8];
        bf8_to_f(aggb[i], av);
        float4 x0 = ((const float4*)x)[2 * i];
        float4 x1 = ((const float4*)x)[2 * i + 1];
        float xv[8] = {x0.x, x0.y, x0.z, x0.w, x1.x, x1.y, x1.z, x1.w};
        float r[8];
#pragma unroll
        for (int j = 0; j < 8; ++j) {
            r[j] = xv[j] + fmaxf(av[j] * A[j] + C[j], 0.f);
            ls[j] += r[j]; lq[j] += r[j] * r[j];
        }
        y1b[i] = f_to_bf8(r);
    }
#pragma unroll
    for (int j = 0; j < 8; ++j) {
        atomicAdd(&zs[c0 + j], ls[j]);
        atomicAdd(&zq[c0 + j], lq[j]);
    }
    __syncthreads();
    int st = (blockIdx.x & (NSTRIPE - 1)) * 256;
    if (tid < 128) {
        atomicAdd(&s2[st + tid], zs[tid]);
        atomicAdd(&s2[st + 128 + tid], zq[tid]);
    }
}

// ---------------- MFMA FFN: z = y2 + relu(y2@W1^T+b1)@W2^T + b2 -> bf16; striped s3 ----------------
__global__ __launch_bounds__(256) void k_ffn2(const uint4* __restrict__ y1b,
                                              const float* __restrict__ s2,
                                              const float* __restrict__ g2,
                                              const float* __restrict__ bl2,
                                              const __bf16* __restrict__ W1b,
                                              const float* __restrict__ b1,
                                              const __bf16* __restrict__ W2b,
                                              const float* __restrict__ b2f,
                                              __bf16* __restrict__ z,
                                              float* __restrict__ s3) {
    __shared__ __bf16 ys[64 * 128];   // swizzled bf16 y2
    __shared__ __bf16 hs[64 * 256];   // swizzled bf16 hidden
    __shared__ float zs[128], zq[128];
    int tid = threadIdx.x;
    int row0 = blockIdx.x * 64;
    int V = NN - row0; if (V > 64) V = 64;
    if (tid < 128) { zs[tid] = 0.f; zq[tid] = 0.f; }

    {   // phase A: ys = bf16(bnl(y1)), swizzled
        int chunk = tid & 15;
        int c0 = chunk * 8;
        float A[8], C[8];
#pragma unroll
        for (int j = 0; j < 8; ++j) {
            int c = c0 + j;
            float m = stripe_sum(s2, c) * (1.f / NN);
            float v = stripe_sum(s2, 128 + c) * (1.f / NN) - m * m;
            float inv = rsqrtf(v + EPS_);
            A[j] = inv * g2[c];
            C[j] = bl2[c] - m * inv * g2[c];
        }
        const uint4* yt = y1b + (size_t)row0 * 16;
        for (int j = 0; j < 4; ++j) {
            int idx = j * 256 + tid;
            int r = idx >> 4;
            uint4 u = make_uint4(0, 0, 0, 0);
            if (r < V) u = yt[idx];
            float f[8];
            bf8_to_f(u, f);
            float o[8];
#pragma unroll
            for (int q = 0; q < 8; ++q) o[q] = f[q] * A[q] + C[q];
            uint4 pk = f_to_bf8(o);
            *reinterpret_cast<uint4*>(&ys[r * 128 + ((chunk ^ (r & 7)) << 3)]) = pk;
        }
    }
    __syncthreads();

    int l = tid & 63, w = tid >> 6;
    int m0 = w * 16, lr = l & 15, lk = (l >> 4) * 8;
    int mrow = m0 + lr;

    // GEMM1: hidden = relu(y2 @ W1^T + b1)
    bf16x8 a1[4];
    for (int kk = 0; kk < 4; ++kk) {
        int k = kk * 32 + lk;
        int sw = ((k >> 3) ^ (mrow & 7)) << 3;
        a1[kk] = *reinterpret_cast<const bf16x8*>(&ys[mrow * 128 + sw]);
    }
    for (int nt = 0; nt < 16; ++nt) {
        int f0 = nt * 16;
        f32x4 acc = {0.f, 0.f, 0.f, 0.f};
        for (int kk = 0; kk < 4; ++kk) {
            bf16x8 b = *reinterpret_cast<const bf16x8*>(&W1b[(f0 + lr) * 128 + kk * 32 + lk]);
            acc = __builtin_amdgcn_mfma_f32_16x16x32_bf16(a1[kk], b, acc, 0, 0, 0);
        }
        int f = f0 + lr;
        float bias = b1[f];
#pragma unroll
        for (int r = 0; r < 4; ++r) {
            int m = m0 + (l >> 4) * 4 + r;
            float hv = fmaxf(acc[r] + bias, 0.f);
            hs[m * 256 + (((f >> 3) ^ (m & 7)) << 3) + (f & 7)] = (__bf16)hv;
        }
    }
    // no barrier: each wave reads only its own 16 hidden rows

    // GEMM2: z = y2 + hidden @ W2^T + b2
    bf16x8 a2[8];
    for (int kk = 0; kk < 8; ++kk) {
        int k = kk * 32 + lk;
        int sw = ((k >> 3) ^ (mrow & 7)) << 3;
        a2[kk] = *reinterpret_cast<const bf16x8*>(&hs[mrow * 256 + sw]);
    }
    for (int ot = 0; ot < 8; ++ot) {
        int o0 = ot * 16;
        f32x4 acc = {0.f, 0.f, 0.f, 0.f};
        for (int kk = 0; kk < 8; ++kk) {
            bf16x8 b = *reinterpret_cast<const bf16x8*>(&W2b[(o0 + lr) * 256 + kk * 32 + lk]);
            acc = __builtin_amdgcn_mfma_f32_16x16x32_bf16(a2[kk], b, acc, 0, 0, 0);
        }
        int o = o0 + lr;
        float bias2 = b2f[o];
        float lsum = 0.f, lsq = 0.f;
#pragma unroll
        for (int r = 0; r < 4; ++r) {
            int m = m0 + (l >> 4) * 4 + r;
            float y2v = (float)ys[m * 128 + (((o >> 3) ^ (m & 7)) << 3) + (o & 7)];
            float zv = y2v + acc[r] + bias2;
            if (m < V) {
                z[(size_t)(row0 + m) * DD + o] = (__bf16)zv;
                lsum += zv; lsq += zv * zv;
            }
        }
        atomicAdd(&zs[o], lsum);
        atomicAdd(&zq[o], lsq);
    }
    __syncthreads();
    int st = (blockIdx.x & (NSTRIPE - 1)) * 256;
    if (tid < 128) {
        atomicAdd(&s3[st + tid], zs[tid]);
        atomicAdd(&s3[st + 128 + tid], zq[tid]);
    }
}

// ---------------- out = bn2(z) ----------------
__global__ __launch_bounds__(256) void k_out(const uint4* __restrict__ zb,
                                             const float* __restrict__ s3,
                                             const float* __restrict__ g,
                                             const float* __restrict__ bb,
                                             float* __restrict__ outp) {
    int tid = threadIdx.x;
    int c0 = (tid & 15) * 8;
    float A[8], C[8];
#pragma unroll
    for (int j = 0; j < 8; ++j) {
        int c = c0 + j;
        float m = stripe_sum(s3, c) * (1.f / NN);
        float v = stripe_sum(s3, 128 + c) * (1.f / NN) - m * m;
        float inv = rsqrtf(v + EPS_);
        A[j] = inv * g[c];
        C[j] = bb[c] - m * inv * g[c];
    }
    float4* o4 = (float4*)outp;
    int step = gridDim.x * 256;
    for (int i = blockIdx.x * 256 + tid; i < NN * 16; i += step) {
        float f[8];
        bf8_to_f(zb[i], f);
        float4 r0, r1;
        r0.x = f[0] * A[0] + C[0]; r0.y = f[1] * A[1] + C[1];
        r0.z = f[2] * A[2] + C[2]; r0.w = f[3] * A[3] + C[3];
        r1.x = f[4] * A[4] + C[4]; r1.y = f[5] * A[5] + C[5];
        r1.z = f[6] * A[6] + C[6]; r1.w = f[7] * A[7] + C[7];
        o4[2 * i] = r0;
        o4[2 * i + 1] = r1;
    }
}

extern "C" void kernel_launch(void* const* d_in, const int* in_sizes, int n_in,
                              void* d_out, int out_size, void* d_ws, size_t ws_size,
                              hipStream_t stream) {
    const float* x     = (const float*)d_in[0];
    const float* ea    = (const float*)d_in[1];
    const float* W     = (const float*)d_in[2];
    const float* b     = (const float*)d_in[3];
    const float* bn_g  = (const float*)d_in[4];
    const float* bn_b  = (const float*)d_in[5];
    const float* bnl_g = (const float*)d_in[6];
    const float* bnl_b = (const float*)d_in[7];
    const float* bn2_g = (const float*)d_in[8];
    const float* bn2_b = (const float*)d_in[9];
    const float* W1    = (const float*)d_in[10];
    const float* b1    = (const float*)d_in[11];
    const float* W2    = (const float*)d_in[12];
    const float* b2    = (const float*)d_in[13];
    const int*   ei    = (const int*)d_in[14];
    float* out = (float*)d_out;

    char* base = (char*)d_ws;
    // [0, 25.6M): h2 bf16; later z bf16 (h2/pair dead once ffn2 runs)
    __bf16* h2   = (__bf16*)base;
    __bf16* z    = (__bf16*)base;
    int*    deg  = (int*)(base + 25600000);       // 400 KB (becomes CSR ptr)
    int2*   pair = (int2*)(base + 26000000);      // 12.8 MB -> ends 38.8 MB
    unsigned int* aggb = (unsigned int*)(base + 51200000);   // bf16 agg, 25.6 MB
    uint4*        y1b  = (uint4*)(base + 76800000);          // bf16 y1, 25.6 MB
    float* stripes = (float*)(base + 102400000);  // 3 x 16 x 256 floats
    float* s1 = stripes;
    float* s2 = stripes + NSTRIPE * 256;
    float* s3 = stripes + 2 * NSTRIPE * 256;
    int*   bsum = (int*)(base + 102449152);       // 98 ints
    __bf16* Wb  = (__bf16*)(base + 102449664);
    __bf16* W1b = Wb + 16384;
    __bf16* W2b = W1b + 32768;

    hipLaunchKernelGGL(k_init,  dim3(391),  dim3(256), 0, stream, W, W1, W2, Wb, W1b, W2b, deg, stripes);
    hipLaunchKernelGGL(k_gemmx, dim3(1563), dim3(256), 0, stream, x, Wb, h2);
    hipLaunchKernelGGL(k_hist,  dim3(6250), dim3(256), 0, stream, ei, deg);
    hipLaunchKernelGGL(k_scanA, dim3(98),   dim3(256), 0, stream, deg, bsum);
    hipLaunchKernelGGL(k_scanB, dim3(98),   dim3(256), 0, stream, deg, bsum);
    hipLaunchKernelGGL(k_fill,  dim3(6250), dim3(256), 0, stream, ei, deg, pair);
    hipLaunchKernelGGL(k_gather, dim3(2048), dim3(256), 0, stream,
                       (const unsigned int*)h2, ea, pair, deg, b, aggb, s1);
    hipLaunchKernelGGL(k_y1,    dim3(2048), dim3(256), 0, stream,
                       x, (const uint4*)aggb, s1, bn_g, bn_b, y1b, s2);
    hipLaunchKernelGGL(k_ffn2,  dim3(1563), dim3(256), 0, stream, y1b, s2, bnl_g, bnl_b,
                       W1b, b1, W2b, b2, z, s3);
    hipLaunchKernelGGL(k_out,   dim3(2048), dim3(256), 0, stream,
                       (const uint4*)z, s3, bn2_g, bn2_b, out);
}

// Round 6
// 707.832 us; speedup vs baseline: 4.8430x; 1.0275x over previous
//
#include <hip/hip_runtime.h>
#include <hip/hip_bf16.h>

#define NN 100000
#define NE 1600000
#define DD 128
#define FF 256
#define NSTRIPE 16
static constexpr float EPS_ = 1e-5f;

typedef __bf16 bf16x4 __attribute__((ext_vector_type(4)));
typedef __bf16 bf16x8 __attribute__((ext_vector_type(8)));
typedef float  f32x4  __attribute__((ext_vector_type(4)));

__device__ inline float bflo(unsigned int u) { return __uint_as_float(u << 16); }
__device__ inline float bfhi(unsigned int u) { return __uint_as_float(u & 0xFFFF0000u); }

__device__ inline unsigned pack_bf16x2(float x, float y) {
    __hip_bfloat162 t;
    t.x = __float2bfloat16(x);
    t.y = __float2bfloat16(y);
    return *reinterpret_cast<unsigned*>(&t);
}
__device__ inline void bf8_to_f(uint4 u, float* f) {
    f[0] = bflo(u.x); f[1] = bfhi(u.x);
    f[2] = bflo(u.y); f[3] = bfhi(u.y);
    f[4] = bflo(u.z); f[5] = bfhi(u.z);
    f[6] = bflo(u.w); f[7] = bfhi(u.w);
}
__device__ inline uint4 f_to_bf8(const float* f) {
    uint4 u;
    u.x = pack_bf16x2(f[0], f[1]);
    u.y = pack_bf16x2(f[2], f[3]);
    u.z = pack_bf16x2(f[4], f[5]);
    u.w = pack_bf16x2(f[6], f[7]);
    return u;
}
__device__ inline float2 ntload2(const float* p) {
    double d = __builtin_nontemporal_load((const double*)p);
    return *reinterpret_cast<float2*>(&d);
}
__device__ inline float stripe_sum(const float* s, int idx) {
    float r = 0.f;
#pragma unroll
    for (int st = 0; st < NSTRIPE; ++st) r += s[st * 256 + idx];
    return r;
}

// ---------------- init: zero deg/stripes + cvt weights + aggb = bias ----------------
__global__ __launch_bounds__(256) void k_init(const float* __restrict__ W,
                                              const float* __restrict__ W1,
                                              const float* __restrict__ W2,
                                              __bf16* __restrict__ Wb,
                                              __bf16* __restrict__ W1b,
                                              __bf16* __restrict__ W2b,
                                              int* __restrict__ deg,
                                              float* __restrict__ stripes,
                                              const float* __restrict__ bias,
                                              uint4* __restrict__ aggb4) {
    int i = blockIdx.x * 256 + threadIdx.x;
    if (i < NN) deg[i] = 0;
    if (i < 3 * NSTRIPE * 256) stripes[i] = 0.f;
    if (i < 16384) Wb[i] = (__bf16)W[i];
    if (i < 32768) W1b[i] = (__bf16)W1[i];
    if (i < 32768) W2b[i] = (__bf16)W2[i];
    if (i < NN * 16) {          // aggb pre-init to broadcast bias (for empty nodes)
        int p = i & 15;         // 8 cols starting at 8*p
        const float4* b4 = (const float4*)bias;
        float4 u0 = b4[2 * p], u1 = b4[2 * p + 1];
        float f[8] = {u0.x, u0.y, u0.z, u0.w, u1.x, u1.y, u1.z, u1.w};
        aggb4[i] = f_to_bf8(f);
    }
}

// ---------------- h = x @ W^T -> bf16, via MFMA ----------------
__global__ __launch_bounds__(256) void k_gemmx(const float* __restrict__ x,
                                               const __bf16* __restrict__ Wb,
                                               __bf16* __restrict__ h2) {
    __shared__ __bf16 xs[64 * 128];
    int tid = threadIdx.x;
    int row0 = blockIdx.x * 64;
    int V = NN - row0; if (V > 64) V = 64;

    {
        int c0 = (tid & 31) * 4;
        for (int j = 0; j < 8; ++j) {
            int idx = j * 256 + tid;
            int r = idx >> 5;
            float4 v = make_float4(0.f, 0.f, 0.f, 0.f);
            if (r < V) v = ((const float4*)(x + (size_t)row0 * DD))[idx];
            bf16x4 bv; bv[0] = (__bf16)v.x; bv[1] = (__bf16)v.y; bv[2] = (__bf16)v.z; bv[3] = (__bf16)v.w;
            int sw = (((c0 >> 3) ^ (r & 7)) << 3) + (c0 & 7);
            *reinterpret_cast<bf16x4*>(&xs[r * 128 + sw]) = bv;
        }
    }
    __syncthreads();

    int l = tid & 63, w = tid >> 6;
    int m0 = w * 16, lr = l & 15, lk = (l >> 4) * 8;
    int mrow = m0 + lr;

    bf16x8 a[4];
    for (int kk = 0; kk < 4; ++kk) {
        int k = kk * 32 + lk;
        int sw = ((k >> 3) ^ (mrow & 7)) << 3;
        a[kk] = *reinterpret_cast<const bf16x8*>(&xs[mrow * 128 + sw]);
    }
    for (int nt = 0; nt < 8; ++nt) {
        int n0 = nt * 16;
        f32x4 acc = {0.f, 0.f, 0.f, 0.f};
        for (int kk = 0; kk < 4; ++kk) {
            bf16x8 b = *reinterpret_cast<const bf16x8*>(&Wb[(n0 + lr) * 128 + kk * 32 + lk]);
            acc = __builtin_amdgcn_mfma_f32_16x16x32_bf16(a[kk], b, acc, 0, 0, 0);
        }
        int n = n0 + lr;
#pragma unroll
        for (int r = 0; r < 4; ++r) {
            int m = m0 + (l >> 4) * 4 + r;
            xs[m * 128 + n] = (__bf16)acc[r];
        }
    }
    for (int i = 0; i < 8; ++i) {
        int j = i * 64 + l;
        int rl = j >> 5;
        int c4 = j & 31;
        int m = m0 + rl;
        if (row0 + m < NN) {
            bf16x4 v = *reinterpret_cast<const bf16x4*>(&xs[m * 128 + c4 * 4]);
            *reinterpret_cast<bf16x4*>(&h2[(size_t)(row0 + m) * 128 + c4 * 4]) = v;
        }
    }
}

// ---------------- deg histogram over dst ----------------
__global__ __launch_bounds__(256) void k_hist(const int* __restrict__ ei,
                                              int* __restrict__ deg) {
    int e = blockIdx.x * 256 + threadIdx.x;
    if (e < NE) atomicAdd(&deg[ei[NE + e]], 1);
}

// ---------------- scan stage A ----------------
__global__ __launch_bounds__(256) void k_scanA(const int* __restrict__ p,
                                               int* __restrict__ bsum) {
    __shared__ int red[256];
    int b = blockIdx.x, tid = threadIdx.x;
    int base = b * 1024;
    int s = 0;
    for (int i = tid; i < 1024; i += 256) {
        int idx = base + i;
        s += (idx < NN) ? p[idx] : 0;
    }
    red[tid] = s;
    __syncthreads();
    for (int d = 128; d > 0; d >>= 1) {
        if (tid < d) red[tid] += red[tid + d];
        __syncthreads();
    }
    if (tid == 0) bsum[b] = red[0];
}

// ---------------- scan stage B ----------------
__global__ __launch_bounds__(256) void k_scanB(int* __restrict__ p,
                                               const int* __restrict__ bsum) {
    __shared__ int part[256];
    __shared__ int boff_sh;
    int b = blockIdx.x, tid = threadIdx.x;
    if (tid == 0) {
        int s = 0;
        for (int i = 0; i < b; ++i) s += bsum[i];
        boff_sh = s;
    }
    int base = b * 1024 + tid * 4;
    int4 v = make_int4(0, 0, 0, 0);
    bool full = (base + 3 < NN);
    if (full) v = *(const int4*)(p + base);
    else {
        if (base + 0 < NN) v.x = p[base + 0];
        if (base + 1 < NN) v.y = p[base + 1];
        if (base + 2 < NN) v.z = p[base + 2];
        if (base + 3 < NN) v.w = p[base + 3];
    }
    int tsum = v.x + v.y + v.z + v.w;
    part[tid] = tsum;
    __syncthreads();
    for (int d = 1; d < 256; d <<= 1) {
        int add = (tid >= d) ? part[tid - d] : 0;
        __syncthreads();
        part[tid] += add;
        __syncthreads();
    }
    int texcl = part[tid] - tsum + boff_sh;
    int4 o;
    o.x = texcl;
    o.y = texcl + v.x;
    o.z = texcl + v.x + v.y;
    o.w = texcl + v.x + v.y + v.z;
    if (full) *(int4*)(p + base) = o;
    else {
        if (base + 0 < NN) p[base + 0] = o.x;
        if (base + 1 < NN) p[base + 1] = o.y;
        if (base + 2 < NN) p[base + 2] = o.z;
        if (base + 3 < NN) p[base + 3] = o.w;
    }
}

// ---------------- fill pair4[pos]={src,e,dst,0} sorted by dst ----------------
__global__ __launch_bounds__(256) void k_fill(const int* __restrict__ ei,
                                              int* __restrict__ ptr,
                                              int4* __restrict__ pair4) {
    int e = blockIdx.x * 256 + threadIdx.x;
    if (e >= NE) return;
    int s = ei[e];
    int d = ei[NE + e];
    int pos = atomicAdd(&ptr[d], 1);
    pair4[pos] = make_int4(s, e, d, 0);
}

// ---------------- stats fixup for empty nodes (expected ~0 of them) ----------------
__global__ __launch_bounds__(256) void k_fixup(const int* __restrict__ ptr,
                                               const float* __restrict__ bias,
                                               float* __restrict__ s1) {
    int i = blockIdx.x * 256 + threadIdx.x;
    if (i >= NN) return;
    int beg = (i == 0) ? 0 : ptr[i - 1];
    if (beg != ptr[i]) return;
    for (int c = 0; c < 128; ++c) {
        float bv = bias[c];
        atomicAdd(&s1[c], bv);
        atomicAdd(&s1[128 + c], bv * bv);
    }
}

// ---------------- gather: steady edge-stream pipeline, node-aligned ranges ----------------
// wave owns nodes whose CSR start lies in [wid*NE/nw, (wid+1)*NE/nw); flush on dst change
__device__ inline int first_node_ge(const int* __restrict__ ptr, int bound) {
    if (bound <= 0) return 0;
    int a = 0, b = NN;
    while (a < b) { int m = (a + b) >> 1; if (ptr[m] >= bound) b = m; else a = m + 1; }
    return a + 1;   // first node n with start(n) >= bound
}

__global__ __launch_bounds__(256) void k_gather(const unsigned int* __restrict__ h2u,
                                                const float* __restrict__ ea,
                                                const int4* __restrict__ pair4,
                                                const int* __restrict__ ptr,
                                                const float* __restrict__ bias,
                                                unsigned int* __restrict__ aggb,
                                                float* __restrict__ s1) {
    __shared__ float zsum[128], zsq[128];
    int tid = threadIdx.x;
    if (tid < 128) { zsum[tid] = 0.f; zsq[tid] = 0.f; }
    __syncthreads();
    int lane = tid & 63;
    int wid = blockIdx.x * 4 + (tid >> 6);
    int nw = gridDim.x * 4;
    float2 bv = ((const float2*)bias)[lane];
    float sx = 0.f, qx = 0.f, sy = 0.f, qy = 0.f;

    long long lo = (long long)wid * NE / nw;
    long long hi = (long long)(wid + 1) * NE / nw;
    int n0 = first_node_ge(ptr, (int)lo);
    int n1 = (wid == nw - 1) ? NN : first_node_ge(ptr, (int)hi);

    if (n0 < n1) {
        int jbeg = (n0 == 0) ? 0 : ptr[n0 - 1];
        int jend = ptr[n1 - 1];
        float ax = 0.f, ay = 0.f;
        int curd = -1;
        int nch = (jend - jbeg + 63) >> 6;
        int4 Qc = make_int4(0, 0, 0, 0), Qn = make_int4(0, 0, 0, 0);
        if (nch > 0) Qc = pair4[jbeg + lane];

        unsigned H0 = 0, H1 = 0, H2 = 0, H3 = 0;
        float2 A0, A1, A2, A3;
        A0 = A1 = A2 = A3 = make_float2(0.f, 0.f);

#define GFLUSH(node) { float fx = ax + bv.x, fy = ay + bv.y; \
        aggb[(size_t)(node) * 64 + lane] = pack_bf16x2(fx, fy); \
        sx += fx; qx += fx * fx; sy += fy; qy += fy * fy; \
        ax = 0.f; ay = 0.f; }
#define GPRO(S) { if (cb + S < jend) { \
        int sn = __shfl(Qc.x, S); int en = __shfl(Qc.y, S); \
        H##S = h2u[(size_t)sn * 64 + lane]; \
        A##S = ntload2(ea + (size_t)en * DD + 2 * lane); } }
#define GSTEP(S) { int kk = k + S; \
        if (cb + kk < jend) { \
            int dk = __shfl(Qc.z, kk); \
            if (dk != curd) { if (curd >= 0) GFLUSH(curd); curd = dk; } \
            ax += fmaxf(bflo(H##S) + A##S.x, 0.f); \
            ay += fmaxf(bfhi(H##S) + A##S.y, 0.f); \
            int kn = kk + 4; \
            if (kn < 64 && cb + kn < jend) { \
                int sn = __shfl(Qc.x, kn); int en = __shfl(Qc.y, kn); \
                H##S = h2u[(size_t)sn * 64 + lane]; \
                A##S = ntload2(ea + (size_t)en * DD + 2 * lane); } } }

        for (int c = 0; c < nch; ++c) {
            int cb = jbeg + (c << 6);
            if (c + 1 < nch) Qn = pair4[cb + 64 + lane];
            GPRO(0) GPRO(1) GPRO(2) GPRO(3)
            for (int k = 0; k < 64; k += 4) {
                GSTEP(0) GSTEP(1) GSTEP(2) GSTEP(3)
            }
            Qc = Qn;
        }
        if (curd >= 0) GFLUSH(curd);
#undef GFLUSH
#undef GPRO
#undef GSTEP
    }

    atomicAdd(&zsum[2 * lane], sx);     atomicAdd(&zsq[2 * lane], qx);
    atomicAdd(&zsum[2 * lane + 1], sy); atomicAdd(&zsq[2 * lane + 1], qy);
    __syncthreads();
    int st = (blockIdx.x & (NSTRIPE - 1)) * 256;
    if (tid < 128) {
        atomicAdd(&s1[st + tid], zsum[tid]);
        atomicAdd(&s1[st + 128 + tid], zsq[tid]);
    }
}

// ---------------- y1 = x + relu(bn1(agg)) -> bf16; striped s2 ----------------
__global__ __launch_bounds__(256) void k_y1(const float* __restrict__ x,
                                            const uint4* __restrict__ aggb,
                                            const float* __restrict__ s1,
                                            const float* __restrict__ g,
                                            const float* __restrict__ bb,
                                            uint4* __restrict__ y1b,
                                            float* __restrict__ s2) {
    __shared__ float zs[128], zq[128];
    int tid = threadIdx.x;
    if (tid < 128) { zs[tid] = 0.f; zq[tid] = 0.f; }
    __syncthreads();
    int c0 = (tid & 15) * 8;
    float A[8], C[8], ls[8] = {0,0,0,0,0,0,0,0}, lq[8] = {0,0,0,0,0,0,0,0};
#pragma unroll
    for (int j = 0; j < 8; ++j) {
        int c = c0 + j;
        float m = stripe_sum(s1, c) * (1.f / NN);
        float v = stripe_sum(s1, 128 + c) * (1.f / NN) - m * m;
        float inv = rsqrtf(v + EPS_);
        A[j] = inv * g[c];
        C[j] = bb[c] - m * inv * g[c];
    }
    int step = gridDim.x * 256;
    for (int i = blockIdx.x * 256 + tid; i < NN * 16; i += step) {
        float av[8];
        bf8_to_f(aggb[i], av);
        float4 x0 = ((const float4*)x)[2 * i];
        float4 x1 = ((const float4*)x)[2 * i + 1];
        float xv[8] = {x0.x, x0.y, x0.z, x0.w, x1.x, x1.y, x1.z, x1.w};
        float r[8];
#pragma unroll
        for (int j = 0; j < 8; ++j) {
            r[j] = xv[j] + fmaxf(av[j] * A[j] + C[j], 0.f);
            ls[j] += r[j]; lq[j] += r[j] * r[j];
        }
        y1b[i] = f_to_bf8(r);
    }
#pragma unroll
    for (int j = 0; j < 8; ++j) {
        atomicAdd(&zs[c0 + j], ls[j]);
        atomicAdd(&zq[c0 + j], lq[j]);
    }
    __syncthreads();
    int st = (blockIdx.x & (NSTRIPE - 1)) * 256;
    if (tid < 128) {
        atomicAdd(&s2[st + tid], zs[tid]);
        atomicAdd(&s2[st + 128 + tid], zq[tid]);
    }
}

// ---------------- MFMA FFN ----------------
__global__ __launch_bounds__(256) void k_ffn2(const uint4* __restrict__ y1b,
                                              const float* __restrict__ s2,
                                              const float* __restrict__ g2,
                                              const float* __restrict__ bl2,
                                              const __bf16* __restrict__ W1b,
                                              const float* __restrict__ b1,
                                              const __bf16* __restrict__ W2b,
                                              const float* __restrict__ b2f,
                                              __bf16* __restrict__ z,
                                              float* __restrict__ s3) {
    __shared__ __bf16 ys[64 * 128];
    __shared__ __bf16 hs[64 * 256];
    __shared__ float zs[128], zq[128];
    int tid = threadIdx.x;
    int row0 = blockIdx.x * 64;
    int V = NN - row0; if (V > 64) V = 64;
    if (tid < 128) { zs[tid] = 0.f; zq[tid] = 0.f; }

    {
        int chunk = tid & 15;
        int c0 = chunk * 8;
        float A[8], C[8];
#pragma unroll
        for (int j = 0; j < 8; ++j) {
            int c = c0 + j;
            float m = stripe_sum(s2, c) * (1.f / NN);
            float v = stripe_sum(s2, 128 + c) * (1.f / NN) - m * m;
            float inv = rsqrtf(v + EPS_);
            A[j] = inv * g2[c];
            C[j] = bl2[c] - m * inv * g2[c];
        }
        const uint4* yt = y1b + (size_t)row0 * 16;
        for (int j = 0; j < 4; ++j) {
            int idx = j * 256 + tid;
            int r = idx >> 4;
            uint4 u = make_uint4(0, 0, 0, 0);
            if (r < V) u = yt[idx];
            float f[8];
            bf8_to_f(u, f);
            float o[8];
#pragma unroll
            for (int q = 0; q < 8; ++q) o[q] = f[q] * A[q] + C[q];
            uint4 pk = f_to_bf8(o);
            *reinterpret_cast<uint4*>(&ys[r * 128 + ((chunk ^ (r & 7)) << 3)]) = pk;
        }
    }
    __syncthreads();

    int l = tid & 63, w = tid >> 6;
    int m0 = w * 16, lr = l & 15, lk = (l >> 4) * 8;
    int mrow = m0 + lr;

    bf16x8 a1[4];
    for (int kk = 0; kk < 4; ++kk) {
        int k = kk * 32 + lk;
        int sw = ((k >> 3) ^ (mrow & 7)) << 3;
        a1[kk] = *reinterpret_cast<const bf16x8*>(&ys[mrow * 128 + sw]);
    }
    for (int nt = 0; nt < 16; ++nt) {
        int f0 = nt * 16;
        f32x4 acc = {0.f, 0.f, 0.f, 0.f};
        for (int kk = 0; kk < 4; ++kk) {
            bf16x8 b = *reinterpret_cast<const bf16x8*>(&W1b[(f0 + lr) * 128 + kk * 32 + lk]);
            acc = __builtin_amdgcn_mfma_f32_16x16x32_bf16(a1[kk], b, acc, 0, 0, 0);
        }
        int f = f0 + lr;
        float bias = b1[f];
#pragma unroll
        for (int r = 0; r < 4; ++r) {
            int m = m0 + (l >> 4) * 4 + r;
            float hv = fmaxf(acc[r] + bias, 0.f);
            hs[m * 256 + (((f >> 3) ^ (m & 7)) << 3) + (f & 7)] = (__bf16)hv;
        }
    }

    bf16x8 a2[8];
    for (int kk = 0; kk < 8; ++kk) {
        int k = kk * 32 + lk;
        int sw = ((k >> 3) ^ (mrow & 7)) << 3;
        a2[kk] = *reinterpret_cast<const bf16x8*>(&hs[mrow * 256 + sw]);
    }
    for (int ot = 0; ot < 8; ++ot) {
        int o0 = ot * 16;
        f32x4 acc = {0.f, 0.f, 0.f, 0.f};
        for (int kk = 0; kk < 8; ++kk) {
            bf16x8 b = *reinterpret_cast<const bf16x8*>(&W2b[(o0 + lr) * 256 + kk * 32 + lk]);
            acc = __builtin_amdgcn_mfma_f32_16x16x32_bf16(a2[kk], b, acc, 0, 0, 0);
        }
        int o = o0 + lr;
        float bias2 = b2f[o];
        float lsum = 0.f, lsq = 0.f;
#pragma unroll
        for (int r = 0; r < 4; ++r) {
            int m = m0 + (l >> 4) * 4 + r;
            float y2v = (float)ys[m * 128 + (((o >> 3) ^ (m & 7)) << 3) + (o & 7)];
            float zv = y2v + acc[r] + bias2;
            if (m < V) {
                z[(size_t)(row0 + m) * DD + o] = (__bf16)zv;
                lsum += zv; lsq += zv * zv;
            }
        }
        atomicAdd(&zs[o], lsum);
        atomicAdd(&zq[o], lsq);
    }
    __syncthreads();
    int st = (blockIdx.x & (NSTRIPE - 1)) * 256;
    if (tid < 128) {
        atomicAdd(&s3[st + tid], zs[tid]);
        atomicAdd(&s3[st + 128 + tid], zq[tid]);
    }
}

// ---------------- out = bn2(z) ----------------
__global__ __launch_bounds__(256) void k_out(const uint4* __restrict__ zb,
                                             const float* __restrict__ s3,
                                             const float* __restrict__ g,
                                             const float* __restrict__ bb,
                                             float* __restrict__ outp) {
    int tid = threadIdx.x;
    int c0 = (tid & 15) * 8;
    float A[8], C[8];
#pragma unroll
    for (int j = 0; j < 8; ++j) {
        int c = c0 + j;
        float m = stripe_sum(s3, c) * (1.f / NN);
        float v = stripe_sum(s3, 128 + c) * (1.f / NN) - m * m;
        float inv = rsqrtf(v + EPS_);
        A[j] = inv * g[c];
        C[j] = bb[c] - m * inv * g[c];
    }
    float4* o4 = (float4*)outp;
    int step = gridDim.x * 256;
    for (int i = blockIdx.x * 256 + tid; i < NN * 16; i += step) {
        float f[8];
        bf8_to_f(zb[i], f);
        float4 r0, r1;
        r0.x = f[0] * A[0] + C[0]; r0.y = f[1] * A[1] + C[1];
        r0.z = f[2] * A[2] + C[2]; r0.w = f[3] * A[3] + C[3];
        r1.x = f[4] * A[4] + C[4]; r1.y = f[5] * A[5] + C[5];
        r1.z = f[6] * A[6] + C[6]; r1.w = f[7] * A[7] + C[7];
        o4[2 * i] = r0;
        o4[2 * i + 1] = r1;
    }
}

extern "C" void kernel_launch(void* const* d_in, const int* in_sizes, int n_in,
                              void* d_out, int out_size, void* d_ws, size_t ws_size,
                              hipStream_t stream) {
    const float* x     = (const float*)d_in[0];
    const float* ea    = (const float*)d_in[1];
    const float* W     = (const float*)d_in[2];
    const float* b     = (const float*)d_in[3];
    const float* bn_g  = (const float*)d_in[4];
    const float* bn_b  = (const float*)d_in[5];
    const float* bnl_g = (const float*)d_in[6];
    const float* bnl_b = (const float*)d_in[7];
    const float* bn2_g = (const float*)d_in[8];
    const float* bn2_b = (const float*)d_in[9];
    const float* W1    = (const float*)d_in[10];
    const float* b1    = (const float*)d_in[11];
    const float* W2    = (const float*)d_in[12];
    const float* b2    = (const float*)d_in[13];
    const int*   ei    = (const int*)d_in[14];
    float* out = (float*)d_out;

    char* base = (char*)d_ws;   // ws is ~3.2 GB; use generous disjoint regions
    __bf16* h2    = (__bf16*)base;                     // 25.6 MB (reused as z later)
    __bf16* z     = (__bf16*)base;
    int*    deg   = (int*)(base + 26000000);           // 400 KB (CSR ptr)
    int4*   pair4 = (int4*)(base + 32000000);          // (NE+64)*16 = ~25.6 MB
    unsigned int* aggb = (unsigned int*)(base + 64000000);   // 25.6 MB
    uint4*        y1b  = (uint4*)(base + 96000000);          // 25.6 MB
    float* stripes = (float*)(base + 128000000);       // 48 KB
    float* s1 = stripes;
    float* s2 = stripes + NSTRIPE * 256;
    float* s3 = stripes + 2 * NSTRIPE * 256;
    int*   bsum = (int*)(base + 128100000);            // 98 ints
    __bf16* Wb  = (__bf16*)(base + 128200000);
    __bf16* W1b = Wb + 16384;
    __bf16* W2b = W1b + 32768;

    hipLaunchKernelGGL(k_init,  dim3(6250), dim3(256), 0, stream,
                       W, W1, W2, Wb, W1b, W2b, deg, stripes, b, (uint4*)aggb);
    hipLaunchKernelGGL(k_gemmx, dim3(1563), dim3(256), 0, stream, x, Wb, h2);
    hipLaunchKernelGGL(k_hist,  dim3(6250), dim3(256), 0, stream, ei, deg);
    hipLaunchKernelGGL(k_scanA, dim3(98),   dim3(256), 0, stream, deg, bsum);
    hipLaunchKernelGGL(k_scanB, dim3(98),   dim3(256), 0, stream, deg, bsum);
    hipLaunchKernelGGL(k_fill,  dim3(6250), dim3(256), 0, stream, ei, deg, pair4);
    hipLaunchKernelGGL(k_gather, dim3(2048), dim3(256), 0, stream,
                       (const unsigned int*)h2, ea, (const int4*)pair4, deg, b, aggb, s1);
    hipLaunchKernelGGL(k_fixup, dim3(391),  dim3(256), 0, stream, deg, b, s1);
    hipLaunchKernelGGL(k_y1,    dim3(2048), dim3(256), 0, stream,
                       x, (const uint4*)aggb, s1, bn_g, bn_b, y1b, s2);
    hipLaunchKernelGGL(k_ffn2,  dim3(1563), dim3(256), 0, stream, y1b, s2, bnl_g, bnl_b,
                       W1b, b1, W2b, b2, z, s3);
    hipLaunchKernelGGL(k_out,   dim3(2048), dim3(256), 0, stream,
                       (const uint4*)z, s3, bn2_g, bn2_b, out);
}